// Round 6
// baseline (724.030 us; speedup 1.0000x reference)
//
#include <hip/hip_runtime.h>
#include <hip/hip_bf16.h>
#include <math.h>

// Problem constants
#define T_TOKENS 8192      // B*S
#define DD 1024            // embed dim
#define HH 2752            // swiglu hidden (43*64)
#define EE 8               // experts
#define BM 256             // M tile / segment alignment
#define MT2 72             // 16384/256 + 8 experts (max 256-row tiles)
#define MT1 144            // 128-row tiles (fallback kernels)

typedef __attribute__((ext_vector_type(8))) short s16x8;
typedef __attribute__((ext_vector_type(4))) float f32x4;

#define VMCNT0 asm volatile("s_waitcnt vmcnt(0)" ::: "memory")
#define VMCNT2 asm volatile("s_waitcnt vmcnt(2)" ::: "memory")
#define VMCNT4 asm volatile("s_waitcnt vmcnt(4)" ::: "memory")
#define SBAR  __builtin_amdgcn_s_barrier()
#define SCHED0 __builtin_amdgcn_sched_barrier(0)

__device__ __forceinline__ unsigned int f2bf1(float f) {
  unsigned int u = __float_as_uint(f);
  return (u + 0x7FFFu + ((u >> 16) & 1u)) >> 16;   // RNE fp32->bf16
}
__device__ __forceinline__ unsigned int f2bf2(float lo, float hi) {
  return f2bf1(lo) | (f2bf1(hi) << 16);
}

__device__ __forceinline__ void gload_lds16(const void* g, void* l) {
  __builtin_amdgcn_global_load_lds((const __attribute__((address_space(1))) void*)g,
                                   (__attribute__((address_space(3))) void*)l, 16, 0, 0);
}

// legacy B-tile swizzle (fallback kernels only)
__device__ __forceinline__ int bswz(int n) {
  return ((n >> 2) & 7) ^ ((n & 3) << 1);
}

// ---------------- router ----------------
__global__ void k_init(int* cursor) {
  if (threadIdx.x < EE) cursor[threadIdx.x] = 0;
}

__global__ void k_router(const float* __restrict__ x, const float* __restrict__ rw,
                         int* __restrict__ topi, float* __restrict__ topw) {
  int t = (blockIdx.x * blockDim.x + threadIdx.x) >> 6;
  int lane = threadIdx.x & 63;
  const float* xr = x + (size_t)t * DD;
  double acc[EE];
#pragma unroll
  for (int e = 0; e < EE; ++e) acc[e] = 0.0;
#pragma unroll
  for (int i = 0; i < DD / 64; ++i) {
    int d = lane + (i << 6);
    double xv = (double)xr[d];
    const float4* rp = (const float4*)(rw + (size_t)d * EE);
    float4 r0 = rp[0], r1 = rp[1];
    acc[0] += xv * (double)r0.x; acc[1] += xv * (double)r0.y;
    acc[2] += xv * (double)r0.z; acc[3] += xv * (double)r0.w;
    acc[4] += xv * (double)r1.x; acc[5] += xv * (double)r1.y;
    acc[6] += xv * (double)r1.z; acc[7] += xv * (double)r1.w;
  }
#pragma unroll
  for (int e = 0; e < EE; ++e) {
    double v = acc[e];
#pragma unroll
    for (int off = 32; off > 0; off >>= 1) v += __shfl_down(v, off, 64);
    acc[e] = v;
  }
  if (lane == 0) {
    int i1 = 0; double l1 = acc[0];
#pragma unroll
    for (int e = 1; e < EE; ++e) if (acc[e] > l1) { l1 = acc[e]; i1 = e; }
    int i2 = -1; double l2 = -1e300;
#pragma unroll
    for (int e = 0; e < EE; ++e) if (e != i1 && acc[e] > l2) { l2 = acc[e]; i2 = e; }
    double ee = exp(l2 - l1);
    float w1 = (float)(1.0 / (1.0 + ee));
    topi[2 * t] = i1; topi[2 * t + 1] = i2;
    topw[2 * t] = w1; topw[2 * t + 1] = 1.0f - w1;
  }
}

__global__ __launch_bounds__(256) void k_assign(int* __restrict__ topi,
                                                int* __restrict__ cursor) {
  __shared__ int hist[EE];
  __shared__ int base[EE];
  int t = blockIdx.x * 256 + threadIdx.x;
  if (threadIdx.x < EE) hist[threadIdx.x] = 0;
  __syncthreads();
  int e0 = topi[2 * t], e1 = topi[2 * t + 1];
  int r0 = atomicAdd(&hist[e0], 1);
  int r1 = atomicAdd(&hist[e1], 1);
  __syncthreads();
  if (threadIdx.x < EE) base[threadIdx.x] = atomicAdd(&cursor[threadIdx.x], hist[threadIdx.x]);
  __syncthreads();
  topi[2 * t]     = e0 | ((base[e0] + r0) << 3);
  topi[2 * t + 1] = e1 | ((base[e1] + r1) << 3);
}

// tpfx in 256-row tile units
__global__ void k_offsets(const int* __restrict__ cursor, int* __restrict__ cnt,
                          int* __restrict__ tpfx) {
  if (threadIdx.x == 0) {
    int acc = 0;
#pragma unroll
    for (int e = 0; e < EE; ++e) {
      cnt[e] = cursor[e];
      tpfx[e] = acc;
      acc += (cursor[e] + 255) >> 8;
    }
    tpfx[EE] = acc;
  }
}

__global__ void k_copy(const float* __restrict__ x, const int* __restrict__ topi,
                       const float* __restrict__ topw, const int* __restrict__ tpfx,
                       int* __restrict__ tok, float* __restrict__ wgt,
                       unsigned short* __restrict__ Xg) {
  int t = (blockIdx.x * blockDim.x + threadIdx.x) >> 6;
  int lane = threadIdx.x & 63;
  int v0 = topi[2 * t], v1 = topi[2 * t + 1];
  int e0 = v0 & 7, e1 = v1 & 7;
  int r0 = (tpfx[e0] << 8) + (v0 >> 3);
  int r1 = (tpfx[e1] << 8) + (v1 >> 3);
  if (lane == 0) {
    tok[r0] = t; wgt[r0] = topw[2 * t];
    tok[r1] = t; wgt[r1] = topw[2 * t + 1];
  }
  const float4* xp = (const float4*)(x + (size_t)t * DD) + (lane << 2);
  float4 a = xp[0], b = xp[1], c = xp[2], d = xp[3];
  uint4 o0, o1;
  o0.x = f2bf2(a.x, a.y); o0.y = f2bf2(a.z, a.w);
  o0.z = f2bf2(b.x, b.y); o0.w = f2bf2(b.z, b.w);
  o1.x = f2bf2(c.x, c.y); o1.y = f2bf2(c.z, c.w);
  o1.z = f2bf2(d.x, d.y); o1.w = f2bf2(d.z, d.w);
  uint4* p0 = (uint4*)(Xg + (size_t)r0 * DD) + (lane << 1);
  p0[0] = o0; p0[1] = o1;
  uint4* p1 = (uint4*)(Xg + (size_t)r1 * DD) + (lane << 1);
  p1[0] = o0; p1[1] = o1;
}

// zero pad rows (up to 255 per expert) -- grid 512 x 256
__global__ void k_padzero(const int* __restrict__ cnt, const int* __restrict__ tpfx,
                          unsigned short* __restrict__ Xg) {
  int wid = (blockIdx.x * blockDim.x + threadIdx.x) >> 6;
  int lane = threadIdx.x & 63;
  int e = wid >> 8, i = wid & 255;
  int c = cnt[e];
  int padded = ((c + 255) >> 8) << 8;
  if (c + i < padded) {
    size_t row = ((size_t)tpfx[e] << 8) + (size_t)(c + i);
    uint4 z = make_uint4(0u, 0u, 0u, 0u);
    uint4* p = (uint4*)(Xg + row * DD) + (lane << 1);
    p[0] = z; p[1] = z;
  }
}

// ---------------- weight transpose+convert: fp32 [R][C] -> bf16 [C][R] ----------------
__global__ __launch_bounds__(256) void k_wtrans(const float* __restrict__ src,
                                                unsigned short* __restrict__ dst,
                                                int R, int C) {
  __shared__ unsigned int Lt[64 * 33];
  int ctn = C >> 6;
  int tiles = (R >> 6) * ctn;
  int bid = blockIdx.x;
  int e = bid / tiles, t = bid % tiles;
  int rt0 = (t / ctn) << 6, ct0 = (t % ctn) << 6;
  const float* s = src + (size_t)e * R * C;
  unsigned short* d = dst + (size_t)e * R * C;
  int tid = threadIdx.x;
  int rp = tid >> 3, cg = tid & 7;
  const float* p0 = s + (size_t)(rt0 + (rp << 1)) * C + ct0 + (cg << 3);
  float4 a0 = *(const float4*)p0;
  float4 a1 = *(const float4*)(p0 + 4);
  float4 b0 = *(const float4*)(p0 + C);
  float4 b1 = *(const float4*)(p0 + C + 4);
  float va[8] = {a0.x, a0.y, a0.z, a0.w, a1.x, a1.y, a1.z, a1.w};
  float vb[8] = {b0.x, b0.y, b0.z, b0.w, b1.x, b1.y, b1.z, b1.w};
#pragma unroll
  for (int j = 0; j < 8; ++j)
    Lt[((cg << 3) + j) * 33 + rp] = f2bf2(va[j], vb[j]);
  __syncthreads();
  int c = tid >> 2, q = tid & 3;
  unsigned int o[8];
#pragma unroll
  for (int i = 0; i < 8; ++i) o[i] = Lt[c * 33 + (q << 3) + i];
  unsigned short* pd = d + (size_t)(ct0 + c) * R + rt0 + (q << 4);
  *(uint4*)pd       = make_uint4(o[0], o[1], o[2], o[3]);
  *(uint4*)(pd + 8) = make_uint4(o[4], o[5], o[6], o[7]);
}

// ---------------- FC1: 256M x 128N/mat x 64K, 8 waves, 4-phase counted-vmcnt ----------------
__global__ __launch_bounds__(512, 2) void k_fc1t(
    const unsigned short* __restrict__ Xg, const unsigned short* __restrict__ wgT,
    const unsigned short* __restrict__ wuT, const int* __restrict__ tpfx,
    unsigned short* __restrict__ hbuf) {
  __shared__ unsigned short Al[2][256 * 64];   // 64 KB
  __shared__ unsigned short Bgl[2][128 * 64];  // 32 KB
  __shared__ unsigned short Bul[2][128 * 64];  // 32 KB
  int flat = blockIdx.x + blockIdx.y * MT2;    // grid (72,22) = 1584 = 8*198
  int swz = (flat & 7) * 198 + (flat >> 3);    // XCD-chunked, mt-fastest
  int mt = swz % MT2;
  int nb = swz / MT2;
  if (mt >= tpfx[EE]) return;
  int e = 0;
  while (mt >= tpfx[e + 1]) ++e;
  int n0 = nb << 7;                             // 128 cols per matrix
  size_t row0 = (size_t)mt << 8;
  const unsigned short* wge = wgT + (size_t)e * DD * HH;
  const unsigned short* wue = wuT + (size_t)e * DD * HH;
  int tid = threadIdx.x, wv = tid >> 6, lane = tid & 63;
  int wm = wv >> 1, wn = wv & 1;                // 4M x 2N: wave = 64M x 64N/mat

  f32x4 zf = {0.f, 0.f, 0.f, 0.f};
  f32x4 ag[4][4], au[4][4];
#pragma unroll
  for (int i = 0; i < 4; ++i)
#pragma unroll
    for (int j = 0; j < 4; ++j) { ag[i][j] = zf; au[i][j] = zf; }

  // staging pointers: A 4 calls/wave, Bg 2, Bu 2; bump +64 elems per issue
  const unsigned short* sA[4]; unsigned short* dA[4];
#pragma unroll
  for (int i = 0; i < 4; ++i) {
    int g = (wv << 2) + i;                      // 0..31 chunks
    int p = (g << 6) + lane;
    int r = p >> 3, c = (p & 7) ^ (r & 7);
    sA[i] = Xg + (row0 + r) * DD + (size_t)(c << 3);
    dA[i] = &Al[0][(size_t)g << 9];
  }
  const unsigned short* sG[2]; const unsigned short* sU[2];
  unsigned short* dG[2]; unsigned short* dU[2];
#pragma unroll
  for (int i = 0; i < 2; ++i) {
    int g = (wv << 1) + i;                      // 0..15 chunks
    int p = (g << 6) + lane;
    int n = p >> 3, c = (p & 7) ^ (n & 7);
    int ng = n0 + n; if (ng >= HH) ng = HH - 1; // tail nb=21 clamp
    sG[i] = wge + (size_t)ng * DD + (size_t)(c << 3);
    sU[i] = wue + (size_t)ng * DD + (size_t)(c << 3);
    dG[i] = &Bgl[0][(size_t)g << 9];
    dU[i] = &Bul[0][(size_t)g << 9];
  }

  // prologue: tile 0 -> buf 0, order A,A,A,A,Bg,Bg,Bu,Bu
  gload_lds16(sA[0], dA[0]); sA[0] += 64;
  gload_lds16(sA[1], dA[1]); sA[1] += 64;
  gload_lds16(sA[2], dA[2]); sA[2] += 64;
  gload_lds16(sA[3], dA[3]); sA[3] += 64;
  gload_lds16(sG[0], dG[0]); sG[0] += 64;
  gload_lds16(sG[1], dG[1]); sG[1] += 64;
  gload_lds16(sU[0], dU[0]); sU[0] += 64;
  gload_lds16(sU[1], dU[1]); sU[1] += 64;

  s16x8 af[4], bg[4], bu[4];
  const int NT = DD / 64;                       // 16
  int cur = 0;
  for (int t = 0; t < NT; ++t) {
    bool iss = (t < NT - 1);
    int wb = cur ^ 1;
    const unsigned short* alb  = &Al[0][0]  + (cur << 14);
    const unsigned short* bglb = &Bgl[0][0] + (cur << 13);
    const unsigned short* bulb = &Bul[0][0] + (cur << 13);
    // ---- P0: consume A(t)+Bg(t) ks0 ----
    VMCNT2;
    SBAR; SCHED0;
    if (iss) {
      gload_lds16(sA[0], dA[0] + (wb << 14)); sA[0] += 64;
      gload_lds16(sA[1], dA[1] + (wb << 14)); sA[1] += 64;
    }
#pragma unroll
    for (int fm = 0; fm < 4; ++fm) {
      int r = (wm << 6) + (fm << 4) + (lane & 15);
      af[fm] = *(const s16x8*)(alb + (r << 6) + (((lane >> 4) ^ (r & 7)) << 3));
    }
#pragma unroll
    for (int fn = 0; fn < 4; ++fn) {
      int n = (wn << 6) + (fn << 4) + (lane & 15);
      bg[fn] = *(const s16x8*)(bglb + (n << 6) + (((lane >> 4) ^ (n & 7)) << 3));
    }
    __builtin_amdgcn_s_setprio(1);
#pragma unroll
    for (int fm = 0; fm < 4; ++fm)
#pragma unroll
      for (int fn = 0; fn < 4; ++fn)
        ag[fm][fn] = __builtin_amdgcn_mfma_f32_16x16x32_bf16(af[fm], bg[fn], ag[fm][fn], 0, 0, 0);
    __builtin_amdgcn_s_setprio(0);
    // ---- P1: consume Bu(t) ks0 ----
    if (iss) { VMCNT2; } else { VMCNT0; }
    SBAR; SCHED0;
    if (iss) {
      gload_lds16(sA[2], dA[2] + (wb << 14)); sA[2] += 64;
      gload_lds16(sA[3], dA[3] + (wb << 14)); sA[3] += 64;
    }
#pragma unroll
    for (int fn = 0; fn < 4; ++fn) {
      int n = (wn << 6) + (fn << 4) + (lane & 15);
      bu[fn] = *(const s16x8*)(bulb + (n << 6) + (((lane >> 4) ^ (n & 7)) << 3));
    }
    __builtin_amdgcn_s_setprio(1);
#pragma unroll
    for (int fm = 0; fm < 4; ++fm)
#pragma unroll
      for (int fn = 0; fn < 4; ++fn)
        au[fm][fn] = __builtin_amdgcn_mfma_f32_16x16x32_bf16(af[fm], bu[fn], au[fm][fn], 0, 0, 0);
    __builtin_amdgcn_s_setprio(0);
    // ---- P2: ks1 gate ----
    SBAR; SCHED0;
    if (iss) {
      gload_lds16(sG[0], dG[0] + (wb << 13)); sG[0] += 64;
      gload_lds16(sG[1], dG[1] + (wb << 13)); sG[1] += 64;
    }
#pragma unroll
    for (int fm = 0; fm < 4; ++fm) {
      int r = (wm << 6) + (fm << 4) + (lane & 15);
      af[fm] = *(const s16x8*)(alb + (r << 6) + (((4 + (lane >> 4)) ^ (r & 7)) << 3));
    }
#pragma unroll
    for (int fn = 0; fn < 4; ++fn) {
      int n = (wn << 6) + (fn << 4) + (lane & 15);
      bg[fn] = *(const s16x8*)(bglb + (n << 6) + (((4 + (lane >> 4)) ^ (n & 7)) << 3));
    }
    __builtin_amdgcn_s_setprio(1);
#pragma unroll
    for (int fm = 0; fm < 4; ++fm)
#pragma unroll
      for (int fn = 0; fn < 4; ++fn)
        ag[fm][fn] = __builtin_amdgcn_mfma_f32_16x16x32_bf16(af[fm], bg[fn], ag[fm][fn], 0, 0, 0);
    __builtin_amdgcn_s_setprio(0);
    // ---- P3: ks1 up ----
    SBAR; SCHED0;
    if (iss) {
      gload_lds16(sU[0], dU[0] + (wb << 13)); sU[0] += 64;
      gload_lds16(sU[1], dU[1] + (wb << 13)); sU[1] += 64;
    }
#pragma unroll
    for (int fn = 0; fn < 4; ++fn) {
      int n = (wn << 6) + (fn << 4) + (lane & 15);
      bu[fn] = *(const s16x8*)(bulb + (n << 6) + (((4 + (lane >> 4)) ^ (n & 7)) << 3));
    }
    __builtin_amdgcn_s_setprio(1);
#pragma unroll
    for (int fm = 0; fm < 4; ++fm)
#pragma unroll
      for (int fn = 0; fn < 4; ++fn)
        au[fm][fn] = __builtin_amdgcn_mfma_f32_16x16x32_bf16(af[fm], bu[fn], au[fm][fn], 0, 0, 0);
    __builtin_amdgcn_s_setprio(0);
    cur ^= 1;
  }

  // epilogue: silu(g)*u -> bf16 (guard tail cols)
#pragma unroll
  for (int fm = 0; fm < 4; ++fm)
#pragma unroll
    for (int fn = 0; fn < 4; ++fn)
#pragma unroll
      for (int j = 0; j < 4; ++j) {
        int cc = n0 + (wn << 6) + (fn << 4) + (lane & 15);
        if (cc < HH) {
          float gv = ag[fm][fn][j];
          float uv = au[fm][fn][j];
          float hv = gv / (1.f + __expf(-gv)) * uv;
          int r = (wm << 6) + (fm << 4) + ((lane >> 4) << 2) + j;
          hbuf[(row0 + r) * HH + (size_t)cc] = (unsigned short)f2bf1(hv);
        }
      }
}

// ---------------- FC2: 256M x 128N x 64K, 8 waves, A triple-buffered (dist 2) ----------------
__global__ __launch_bounds__(512, 2) void k_fc2t(
    const unsigned short* __restrict__ hbuf, const unsigned short* __restrict__ wdT,
    const int* __restrict__ cnt, const int* __restrict__ tpfx,
    const int* __restrict__ tok, const float* __restrict__ wgt,
    float* __restrict__ out) {
  __shared__ unsigned short Al[3][256 * 64];   // 96 KB (triple buffer, dist-2 A prefetch)
  __shared__ unsigned short Bl[2][128 * 64];   // 32 KB
  int flat = blockIdx.x + blockIdx.y * MT2;    // grid (72,8) = 576 = 8*72
  int swz = (flat & 7) * 72 + (flat >> 3);
  int mt = swz % MT2;
  int nb = swz / MT2;
  if (mt >= tpfx[EE]) return;
  int e = 0;
  while (mt >= tpfx[e + 1]) ++e;
  int n0 = nb << 7;
  size_t row0 = (size_t)mt << 8;
  int mrem = cnt[e] - ((mt - tpfx[e]) << 8);
  if (mrem > 256) mrem = 256;
  const unsigned short* wde = wdT + (size_t)e * DD * HH;  // [1024][2752]
  int tid = threadIdx.x, wv = tid >> 6, lane = tid & 63;
  int wm = wv >> 1, wn = wv & 1;                // 4M x 2N: wave 64x64

  f32x4 zf = {0.f, 0.f, 0.f, 0.f};
  f32x4 acc[4][4];
#pragma unroll
  for (int i = 0; i < 4; ++i)
#pragma unroll
    for (int j = 0; j < 4; ++j) acc[i][j] = zf;

  const unsigned short* sA[4]; unsigned short* dA[4];
#pragma unroll
  for (int i = 0; i < 4; ++i) {
    int g = (wv << 2) + i;
    int p = (g << 6) + lane;
    int r = p >> 3, c = (p & 7) ^ (r & 7);
    sA[i] = hbuf + (row0 + r) * HH + (size_t)(c << 3);
    dA[i] = &Al[0][(size_t)g << 9];
  }
  const unsigned short* sB[2]; unsigned short* dB[2];
#pragma unroll
  for (int i = 0; i < 2; ++i) {
    int g = (wv << 1) + i;
    int p = (g << 6) + lane;
    int n = p >> 3, c = (p & 7) ^ (n & 7);
    sB[i] = wde + (size_t)(n0 + n) * HH + (size_t)(c << 3);
    dB[i] = &Bl[0][(size_t)g << 9];
  }

  // prologue queue: A(0)x4, B(0)x2, A(1)x4  -> matches steady wait(4)
  gload_lds16(sA[0], dA[0]); sA[0] += 64;
  gload_lds16(sA[1], dA[1]); sA[1] += 64;
  gload_lds16(sA[2], dA[2]); sA[2] += 64;
  gload_lds16(sA[3], dA[3]); sA[3] += 64;
  gload_lds16(sB[0], dB[0]); sB[0] += 64;
  gload_lds16(sB[1], dB[1]); sB[1] += 64;
  gload_lds16(sA[0], dA[0] + 16384); sA[0] += 64;
  gload_lds16(sA[1], dA[1] + 16384); sA[1] += 64;
  gload_lds16(sA[2], dA[2] + 16384); sA[2] += 64;
  gload_lds16(sA[3], dA[3] + 16384); sA[3] += 64;

  s16x8 af[4], bf[4];
  const int NT = HH / 64;                       // 43
  int ca = 0, cb = 0;
  for (int t = 0; t < NT; ++t) {
    bool issB = (t + 1 < NT);
    bool issA = (t + 2 < NT);
    int wa = ca + 2; if (wa >= 3) wa -= 3;      // A write buf = (t+2)%3
    int wbb = cb ^ 1;                           // B write buf
    const unsigned short* alb = &Al[0][0] + (ca << 14);
    const unsigned short* blb = &Bl[0][0] + (cb << 13);
    // ---- P0 (ks0) ----
    if (t == NT - 1) { VMCNT0; } else { VMCNT4; }
    SBAR; SCHED0;
    if (issB) {
      gload_lds16(sB[0], dB[0] + (wbb << 13)); sB[0] += 64;
      gload_lds16(sB[1], dB[1] + (wbb << 13)); sB[1] += 64;
    }
    if (issA) {
      gload_lds16(sA[0], dA[0] + (wa << 14)); sA[0] += 64;
      gload_lds16(sA[1], dA[1] + (wa << 14)); sA[1] += 64;
    }
#pragma unroll
    for (int fm = 0; fm < 4; ++fm) {
      int r = (wm << 6) + (fm << 4) + (lane & 15);
      af[fm] = *(const s16x8*)(alb + (r << 6) + (((lane >> 4) ^ (r & 7)) << 3));
    }
#pragma unroll
    for (int fn = 0; fn < 4; ++fn) {
      int n = (wn << 6) + (fn << 4) + (lane & 15);
      bf[fn] = *(const s16x8*)(blb + (n << 6) + (((lane >> 4) ^ (n & 7)) << 3));
    }
    __builtin_amdgcn_s_setprio(1);
#pragma unroll
    for (int fm = 0; fm < 4; ++fm)
#pragma unroll
      for (int fn = 0; fn < 4; ++fn)
        acc[fm][fn] = __builtin_amdgcn_mfma_f32_16x16x32_bf16(af[fm], bf[fn], acc[fm][fn], 0, 0, 0);
    __builtin_amdgcn_s_setprio(0);
    // ---- P1 (ks1) ----
    SBAR; SCHED0;
    if (issA) {
      gload_lds16(sA[2], dA[2] + (wa << 14)); sA[2] += 64;
      gload_lds16(sA[3], dA[3] + (wa << 14)); sA[3] += 64;
    }
#pragma unroll
    for (int fm = 0; fm < 4; ++fm) {
      int r = (wm << 6) + (fm << 4) + (lane & 15);
      af[fm] = *(const s16x8*)(alb + (r << 6) + (((4 + (lane >> 4)) ^ (r & 7)) << 3));
    }
#pragma unroll
    for (int fn = 0; fn < 4; ++fn) {
      int n = (wn << 6) + (fn << 4) + (lane & 15);
      bf[fn] = *(const s16x8*)(blb + (n << 6) + (((4 + (lane >> 4)) ^ (n & 7)) << 3));
    }
    __builtin_amdgcn_s_setprio(1);
#pragma unroll
    for (int fm = 0; fm < 4; ++fm)
#pragma unroll
      for (int fn = 0; fn < 4; ++fn)
        acc[fm][fn] = __builtin_amdgcn_mfma_f32_16x16x32_bf16(af[fm], bf[fn], acc[fm][fn], 0, 0, 0);
    __builtin_amdgcn_s_setprio(0);
    ca = ca + 1; if (ca >= 3) ca = 0;
    cb ^= 1;
  }

  // epilogue: weighted scatter-add
#pragma unroll
  for (int fm = 0; fm < 4; ++fm)
#pragma unroll
    for (int j = 0; j < 4; ++j) {
      int r = (wm << 6) + (fm << 4) + ((lane >> 4) << 2) + j;
      if (r < mrem) {
        int tk = tok[row0 + r];
        float cw = wgt[row0 + r];
        float* ob = out + (size_t)tk * DD + (size_t)(n0 + (wn << 6) + (lane & 15));
#pragma unroll
        for (int fn = 0; fn < 4; ++fn)
          atomicAdd(ob + (fn << 4), acc[fm][fn][j] * cw);
      }
    }
}

// ================= fallback kernels (128-row tiles over 256-aligned segments) =================
__global__ __launch_bounds__(256) void k_fc1_cv(
    const unsigned short* __restrict__ Xg, const float* __restrict__ wg,
    const float* __restrict__ wu, const int* __restrict__ tpfx,
    unsigned short* __restrict__ hbuf) {
  __shared__ unsigned short Al[128 * 64];
  __shared__ unsigned short Bgl[64 * 64];
  __shared__ unsigned short Bul[64 * 64];
  int mt = blockIdx.x;
  if (mt >= 2 * tpfx[EE]) return;
  int e = 0;
  while (mt >= 2 * tpfx[e + 1]) ++e;
  int n0 = blockIdx.y << 6;
  size_t row0 = (size_t)mt << 7;
  const float* wge = wg + (size_t)e * DD * HH;
  const float* wue = wu + (size_t)e * DD * HH;
  int tid = threadIdx.x, wv = tid >> 6, lane = tid & 63;
  int wm = wv >> 1, wn = wv & 1;
  f32x4 zf = {0.f, 0.f, 0.f, 0.f};
  f32x4 ag[4][2], au[4][2];
#pragma unroll
  for (int i = 0; i < 4; ++i)
#pragma unroll
    for (int j = 0; j < 2; ++j) { ag[i][j] = zf; au[i][j] = zf; }
  for (int kt = 0; kt < DD / 64; ++kt) {
    int k0 = kt << 6;
#pragma unroll
    for (int i = 0; i < 4; ++i) {
      int g = (wv << 2) + i;
      int p = (g << 6) + lane;
      int r = p >> 3, c = (p & 7) ^ (r & 7);
      gload_lds16(Xg + (row0 + r) * DD + (size_t)(k0 + (c << 3)), Al + ((size_t)g << 9));
    }
#pragma unroll
    for (int a2 = 0; a2 < 2; ++a2) {
      int idx = tid + (a2 << 8);
      int kk = (idx >> 4) << 1;
      int nn = (idx & 15) << 2;
      const float* pg = wge + (size_t)(k0 + kk) * HH + (n0 + nn);
      const float* pu = wue + (size_t)(k0 + kk) * HH + (n0 + nn);
      float4 g0 = *(const float4*)pg;
      float4 g1 = *(const float4*)(pg + HH);
      float4 u0 = *(const float4*)pu;
      float4 u1 = *(const float4*)(pu + HH);
      const float* g0f = (const float*)&g0; const float* g1f = (const float*)&g1;
      const float* u0f = (const float*)&u0; const float* u1f = (const float*)&u1;
      int kb = kk << 1, ch = kb >> 4, inb = kb & 15;
#pragma unroll
      for (int j = 0; j < 4; ++j) {
        int n = nn + j;
        int off = (n << 7) + ((ch ^ bswz(n)) << 4) + inb;
        *(unsigned int*)((char*)Bgl + off) = f2bf2(g0f[j], g1f[j]);
        *(unsigned int*)((char*)Bul + off) = f2bf2(u0f[j], u1f[j]);
      }
    }
    __syncthreads();
#pragma unroll
    for (int ks = 0; ks < 2; ++ks) {
      int cch = (ks << 2) + (lane >> 4);
      s16x8 af[4];
#pragma unroll
      for (int fm = 0; fm < 4; ++fm) {
        int r = (wm << 6) + (fm << 4) + (lane & 15);
        af[fm] = *(const s16x8*)(Al + (r << 6) + ((cch ^ (r & 7)) << 3));
      }
      s16x8 bg[2], bu[2];
#pragma unroll
      for (int fn = 0; fn < 2; ++fn) {
        int n = (wn << 5) + (fn << 4) + (lane & 15);
        int o = (n << 6) + ((cch ^ bswz(n)) << 3);
        bg[fn] = *(const s16x8*)(Bgl + o);
        bu[fn] = *(const s16x8*)(Bul + o);
      }
#pragma unroll
      for (int fm = 0; fm < 4; ++fm)
#pragma unroll
        for (int fn = 0; fn < 2; ++fn) {
          ag[fm][fn] = __builtin_amdgcn_mfma_f32_16x16x32_bf16(af[fm], bg[fn], ag[fm][fn], 0, 0, 0);
          au[fm][fn] = __builtin_amdgcn_mfma_f32_16x16x32_bf16(af[fm], bu[fn], au[fm][fn], 0, 0, 0);
        }
    }
    __syncthreads();
  }
#pragma unroll
  for (int fm = 0; fm < 4; ++fm)
#pragma unroll
    for (int fn = 0; fn < 2; ++fn)
#pragma unroll
      for (int j = 0; j < 4; ++j) {
        float gv = ag[fm][fn][j];
        float uv = au[fm][fn][j];
        float hv = gv / (1.f + __expf(-gv)) * uv;
        int r = (wm << 6) + (fm << 4) + ((lane >> 4) << 2) + j;
        int cc = (wn << 5) + (fn << 4) + (lane & 15);
        hbuf[(row0 + r) * HH + (size_t)(n0 + cc)] = (unsigned short)f2bf1(hv);
      }
}

__global__ __launch_bounds__(256) void k_fc2_cv(
    const unsigned short* __restrict__ hbuf, const float* __restrict__ wd,
    const int* __restrict__ cnt, const int* __restrict__ tpfx,
    const int* __restrict__ tok, const float* __restrict__ wgt,
    float* __restrict__ out) {
  __shared__ unsigned short Al[128 * 64];
  __shared__ unsigned short Bl[128 * 64];
  int mt = blockIdx.x;
  if (mt >= 2 * tpfx[EE]) return;
  int e = 0;
  while (mt >= 2 * tpfx[e + 1]) ++e;
  int n0 = blockIdx.y << 7;
  size_t row0 = (size_t)mt << 7;
  int mrem = cnt[e] - ((mt - 2 * tpfx[e]) << 7);
  if (mrem > 128) mrem = 128;
  const float* wde = wd + (size_t)e * HH * DD;
  int tid = threadIdx.x, wv = tid >> 6, lane = tid & 63;
  int wm = wv >> 1, wn = wv & 1;
  f32x4 zf = {0.f, 0.f, 0.f, 0.f};
  f32x4 acc[4][4];
#pragma unroll
  for (int i = 0; i < 4; ++i)
#pragma unroll
    for (int j = 0; j < 4; ++j) acc[i][j] = zf;
  for (int kt = 0; kt < HH / 64; ++kt) {
    int k0 = kt << 6;
#pragma unroll
    for (int i = 0; i < 4; ++i) {
      int g = (wv << 2) + i;
      int p = (g << 6) + lane;
      int r = p >> 3, c = (p & 7) ^ (r & 7);
      gload_lds16(hbuf + (row0 + r) * HH + (size_t)(k0 + (c << 3)), Al + ((size_t)g << 9));
    }
#pragma unroll
    for (int a2 = 0; a2 < 4; ++a2) {
      int idx = tid + (a2 << 8);
      int kk = (idx >> 5) << 1;
      int nn = (idx & 31) << 2;
      const float* pb = wde + (size_t)(k0 + kk) * DD + (n0 + nn);
      float4 b0 = *(const float4*)pb;
      float4 b1 = *(const float4*)(pb + DD);
      const float* b0f = (const float*)&b0;
      const float* b1f = (const float*)&b1;
      int kb = kk << 1, ch = kb >> 4, inb = kb & 15;
#pragma unroll
      for (int j = 0; j < 4; ++j) {
        int n = nn + j;
        int off = (n << 7) + ((ch ^ bswz(n)) << 4) + inb;
        *(unsigned int*)((char*)Bl + off) = f2bf2(b0f[j], b1f[j]);
      }
    }
    __syncthreads();
#pragma unroll
    for (int ks = 0; ks < 2; ++ks) {
      int cch = (ks << 2) + (lane >> 4);
      s16x8 af[4], bf[4];
#pragma unroll
      for (int fm = 0; fm < 4; ++fm) {
        int r = (wm << 6) + (fm << 4) + (lane & 15);
        af[fm] = *(const s16x8*)(Al + (r << 6) + ((cch ^ (r & 7)) << 3));
      }
#pragma unroll
      for (int fn = 0; fn < 4; ++fn) {
        int n = (wn << 6) + (fn << 4) + (lane & 15);
        bf[fn] = *(const s16x8*)(Bl + (n << 6) + ((cch ^ bswz(n)) << 3));
      }
#pragma unroll
      for (int fm = 0; fm < 4; ++fm)
#pragma unroll
        for (int fn = 0; fn < 4; ++fn)
          acc[fm][fn] = __builtin_amdgcn_mfma_f32_16x16x32_bf16(af[fm], bf[fn], acc[fm][fn], 0, 0, 0);
    }
    __syncthreads();
  }
#pragma unroll
  for (int fm = 0; fm < 4; ++fm)
#pragma unroll
    for (int j = 0; j < 4; ++j) {
      int r = (wm << 6) + (fm << 4) + ((lane >> 4) << 2) + j;
      if (r < mrem) {
        int tk = tok[row0 + r];
        float cw = wgt[row0 + r];
        float* ob = out + (size_t)tk * DD + (size_t)(n0 + (wn << 6) + (lane & 15));
#pragma unroll
        for (int fn = 0; fn < 4; ++fn)
          atomicAdd(ob + (fn << 4), acc[fm][fn][j] * cw);
      }
    }
}

extern "C" void kernel_launch(void* const* d_in, const int* in_sizes, int n_in,
                              void* d_out, int out_size, void* d_ws, size_t ws_size,
                              hipStream_t stream) {
  const float* x  = (const float*)d_in[0];
  const float* rw = (const float*)d_in[1];
  const float* wg = (const float*)d_in[2];
  const float* wu = (const float*)d_in[3];
  const float* wd = (const float*)d_in[4];
  float* out = (float*)d_out;

  // workspace layout (256-row padded segments; max 18432 gathered rows)
  char* w = (char*)d_ws;
  int* cnt    = (int*)(w + 0);
  int* cursor = (int*)(w + 32);
  int* tpfx   = (int*)(w + 64);
  int* topi   = (int*)(w + 256);                      // 16384 ints
  float* topw = (float*)(w + 65792);                  // 16384 f32
  int* tok    = (int*)(w + 131328);                   // 18432 ints
  float* wgt  = (float*)(w + 205056);                 // 18432 f32
  unsigned short* Xg  = (unsigned short*)(w + 278784);        // 37,748,736 B
  unsigned short* hb  = (unsigned short*)(w + 38027520ULL);   // 101,449,728 B
  unsigned short* wgT = (unsigned short*)(w + 139477248ULL);  // 45,088,768 B
  unsigned short* wuT = (unsigned short*)(w + 184566016ULL);  // 45,088,768 B
  unsigned short* wdT = wgT;  // reuses wgT slot AFTER fc1
  const size_t NEED = 229654784ULL;

  hipMemsetAsync(d_out, 0, (size_t)T_TOKENS * DD * sizeof(float), stream);
  k_init<<<1, 64, 0, stream>>>(cursor);
  k_router<<<T_TOKENS / 4, 256, 0, stream>>>(x, rw, topi, topw);
  k_assign<<<T_TOKENS / 256, 256, 0, stream>>>(topi, cursor);
  k_offsets<<<1, 64, 0, stream>>>(cursor, cnt, tpfx);
  k_copy<<<T_TOKENS / 4, 256, 0, stream>>>(x, topi, topw, tpfx, tok, wgt, Xg);
  k_padzero<<<512, 256, 0, stream>>>(cnt, tpfx, Xg);

  if (ws_size >= NEED) {
    k_wtrans<<<EE * 16 * 43, 256, 0, stream>>>(wg, wgT, DD, HH);
    k_wtrans<<<EE * 16 * 43, 256, 0, stream>>>(wu, wuT, DD, HH);
    k_fc1t<<<dim3(MT2, 22), 512, 0, stream>>>(Xg, wgT, wuT, tpfx, hb);
    k_wtrans<<<EE * 43 * 16, 256, 0, stream>>>(wd, wdT, HH, DD);  // over wgT slot
    k_fc2t<<<dim3(MT2, 8), 512, 0, stream>>>(hb, wdT, cnt, tpfx, tok, wgt, out);
  } else {
    k_fc1_cv<<<dim3(MT1, HH / 64), 256, 0, stream>>>(Xg, wg, wu, tpfx, hb);
    k_fc2_cv<<<dim3(MT1, DD / 128), 256, 0, stream>>>(hb, wd, cnt, tpfx, tok, wgt, out);
  }
}

// Round 7
// 569.763 us; speedup vs baseline: 1.2708x; 1.2708x over previous
//
#include <hip/hip_runtime.h>
#include <hip/hip_bf16.h>
#include <math.h>

// Problem constants
#define T_TOKENS 8192      // B*S
#define DD 1024            // embed dim
#define HH 2752            // swiglu hidden (43*64)
#define EE 8               // experts
#define NBLK 256           // persistent blocks (1 per CU)
#define MT1 144            // 128-row tiles (fallback kernels)

typedef __attribute__((ext_vector_type(8))) short s16x8;
typedef __attribute__((ext_vector_type(4))) float f32x4;

#define VMCNT0 asm volatile("s_waitcnt vmcnt(0)" ::: "memory")
#define VMCNT2 asm volatile("s_waitcnt vmcnt(2)" ::: "memory")
#define LGKM0  asm volatile("s_waitcnt lgkmcnt(0)" ::: "memory")
#define SBAR   __builtin_amdgcn_s_barrier()
#define SCHED0 __builtin_amdgcn_sched_barrier(0)

__device__ __forceinline__ unsigned int f2bf1(float f) {
  unsigned int u = __float_as_uint(f);
  return (u + 0x7FFFu + ((u >> 16) & 1u)) >> 16;   // RNE fp32->bf16
}
__device__ __forceinline__ unsigned int f2bf2(float lo, float hi) {
  return f2bf1(lo) | (f2bf1(hi) << 16);
}

__device__ __forceinline__ void gload_lds16(const void* g, void* l) {
  __builtin_amdgcn_global_load_lds((const __attribute__((address_space(1))) void*)g,
                                   (__attribute__((address_space(3))) void*)l, 16, 0, 0);
}

// legacy B-tile swizzle (fallback kernels only)
__device__ __forceinline__ int bswz(int n) {
  return ((n >> 2) & 7) ^ ((n & 3) << 1);
}

// ---------------- router ----------------
__global__ void k_init(int* cursor) {
  if (threadIdx.x < EE) cursor[threadIdx.x] = 0;
}

__global__ void k_router(const float* __restrict__ x, const float* __restrict__ rw,
                         int* __restrict__ topi, float* __restrict__ topw) {
  int t = (blockIdx.x * blockDim.x + threadIdx.x) >> 6;
  int lane = threadIdx.x & 63;
  const float* xr = x + (size_t)t * DD;
  double acc[EE];
#pragma unroll
  for (int e = 0; e < EE; ++e) acc[e] = 0.0;
#pragma unroll
  for (int i = 0; i < DD / 64; ++i) {
    int d = lane + (i << 6);
    double xv = (double)xr[d];
    const float4* rp = (const float4*)(rw + (size_t)d * EE);
    float4 r0 = rp[0], r1 = rp[1];
    acc[0] += xv * (double)r0.x; acc[1] += xv * (double)r0.y;
    acc[2] += xv * (double)r0.z; acc[3] += xv * (double)r0.w;
    acc[4] += xv * (double)r1.x; acc[5] += xv * (double)r1.y;
    acc[6] += xv * (double)r1.z; acc[7] += xv * (double)r1.w;
  }
#pragma unroll
  for (int e = 0; e < EE; ++e) {
    double v = acc[e];
#pragma unroll
    for (int off = 32; off > 0; off >>= 1) v += __shfl_down(v, off, 64);
    acc[e] = v;
  }
  if (lane == 0) {
    int i1 = 0; double l1 = acc[0];
#pragma unroll
    for (int e = 1; e < EE; ++e) if (acc[e] > l1) { l1 = acc[e]; i1 = e; }
    int i2 = -1; double l2 = -1e300;
#pragma unroll
    for (int e = 0; e < EE; ++e) if (e != i1 && acc[e] > l2) { l2 = acc[e]; i2 = e; }
    double ee = exp(l2 - l1);
    float w1 = (float)(1.0 / (1.0 + ee));
    topi[2 * t] = i1; topi[2 * t + 1] = i2;
    topw[2 * t] = w1; topw[2 * t + 1] = 1.0f - w1;
  }
}

__global__ __launch_bounds__(256) void k_assign(int* __restrict__ topi,
                                                int* __restrict__ cursor) {
  __shared__ int hist[EE];
  __shared__ int base[EE];
  int t = blockIdx.x * 256 + threadIdx.x;
  if (threadIdx.x < EE) hist[threadIdx.x] = 0;
  __syncthreads();
  int e0 = topi[2 * t], e1 = topi[2 * t + 1];
  int r0 = atomicAdd(&hist[e0], 1);
  int r1 = atomicAdd(&hist[e1], 1);
  __syncthreads();
  if (threadIdx.x < EE) base[threadIdx.x] = atomicAdd(&cursor[threadIdx.x], hist[threadIdx.x]);
  __syncthreads();
  topi[2 * t]     = e0 | ((base[e0] + r0) << 3);
  topi[2 * t + 1] = e1 | ((base[e1] + r1) << 3);
}

// tpfx in 256-row tile units
__global__ void k_offsets(const int* __restrict__ cursor, int* __restrict__ cnt,
                          int* __restrict__ tpfx) {
  if (threadIdx.x == 0) {
    int acc = 0;
#pragma unroll
    for (int e = 0; e < EE; ++e) {
      cnt[e] = cursor[e];
      tpfx[e] = acc;
      acc += (cursor[e] + 255) >> 8;
    }
    tpfx[EE] = acc;
  }
}

__global__ void k_copy(const float* __restrict__ x, const int* __restrict__ topi,
                       const float* __restrict__ topw, const int* __restrict__ tpfx,
                       int* __restrict__ tok, float* __restrict__ wgt,
                       unsigned short* __restrict__ Xg) {
  int t = (blockIdx.x * blockDim.x + threadIdx.x) >> 6;
  int lane = threadIdx.x & 63;
  int v0 = topi[2 * t], v1 = topi[2 * t + 1];
  int e0 = v0 & 7, e1 = v1 & 7;
  int r0 = (tpfx[e0] << 8) + (v0 >> 3);
  int r1 = (tpfx[e1] << 8) + (v1 >> 3);
  if (lane == 0) {
    tok[r0] = t; wgt[r0] = topw[2 * t];
    tok[r1] = t; wgt[r1] = topw[2 * t + 1];
  }
  const float4* xp = (const float4*)(x + (size_t)t * DD) + (lane << 2);
  float4 a = xp[0], b = xp[1], c = xp[2], d = xp[3];
  uint4 o0, o1;
  o0.x = f2bf2(a.x, a.y); o0.y = f2bf2(a.z, a.w);
  o0.z = f2bf2(b.x, b.y); o0.w = f2bf2(b.z, b.w);
  o1.x = f2bf2(c.x, c.y); o1.y = f2bf2(c.z, c.w);
  o1.z = f2bf2(d.x, d.y); o1.w = f2bf2(d.z, d.w);
  uint4* p0 = (uint4*)(Xg + (size_t)r0 * DD) + (lane << 1);
  p0[0] = o0; p0[1] = o1;
  uint4* p1 = (uint4*)(Xg + (size_t)r1 * DD) + (lane << 1);
  p1[0] = o0; p1[1] = o1;
}

// zero pad rows (up to 255 per expert)
__global__ void k_padzero(const int* __restrict__ cnt, const int* __restrict__ tpfx,
                          unsigned short* __restrict__ Xg) {
  int wid = (blockIdx.x * blockDim.x + threadIdx.x) >> 6;
  int lane = threadIdx.x & 63;
  int e = wid >> 8, i = wid & 255;
  int c = cnt[e];
  int padded = ((c + 255) >> 8) << 8;
  if (c + i < padded) {
    size_t row = ((size_t)tpfx[e] << 8) + (size_t)(c + i);
    uint4 z = make_uint4(0u, 0u, 0u, 0u);
    uint4* p = (uint4*)(Xg + row * DD) + (lane << 1);
    p[0] = z; p[1] = z;
  }
}

// ---------------- weight transpose+convert: fp32 [R][C] -> bf16 [C][R] ----------------
__global__ __launch_bounds__(256) void k_wtrans(const float* __restrict__ src,
                                                unsigned short* __restrict__ dst,
                                                int R, int C) {
  __shared__ unsigned int Lt[64 * 33];
  int ctn = C >> 6;
  int tiles = (R >> 6) * ctn;
  int bid = blockIdx.x;
  int e = bid / tiles, t = bid % tiles;
  int rt0 = (t / ctn) << 6, ct0 = (t % ctn) << 6;
  const float* s = src + (size_t)e * R * C;
  unsigned short* d = dst + (size_t)e * R * C;
  int tid = threadIdx.x;
  int rp = tid >> 3, cg = tid & 7;
  const float* p0 = s + (size_t)(rt0 + (rp << 1)) * C + ct0 + (cg << 3);
  float4 a0 = *(const float4*)p0;
  float4 a1 = *(const float4*)(p0 + 4);
  float4 b0 = *(const float4*)(p0 + C);
  float4 b1 = *(const float4*)(p0 + C + 4);
  float va[8] = {a0.x, a0.y, a0.z, a0.w, a1.x, a1.y, a1.z, a1.w};
  float vb[8] = {b0.x, b0.y, b0.z, b0.w, b1.x, b1.y, b1.z, b1.w};
#pragma unroll
  for (int j = 0; j < 8; ++j)
    Lt[((cg << 3) + j) * 33 + rp] = f2bf2(va[j], vb[j]);
  __syncthreads();
  int c = tid >> 2, q = tid & 3;
  unsigned int o[8];
#pragma unroll
  for (int i = 0; i < 8; ++i) o[i] = Lt[c * 33 + (q << 3) + i];
  unsigned short* pd = d + (size_t)(ct0 + c) * R + rt0 + (q << 4);
  *(uint4*)pd       = make_uint4(o[0], o[1], o[2], o[3]);
  *(uint4*)(pd + 8) = make_uint4(o[4], o[5], o[6], o[7]);
}

// ---------------- FC1: persistent blocks, continuous 4-phase pipeline ----------------
// tile 256M x 128N/mat x 64K; 8 waves (4Mx2N); wave 64x64 per matrix
__global__ __launch_bounds__(512, 1) void k_fc1t(
    const unsigned short* __restrict__ Xg, const unsigned short* __restrict__ wgT,
    const unsigned short* __restrict__ wuT, const int* __restrict__ tpfx,
    unsigned short* __restrict__ hbuf) {
  __shared__ unsigned short Al[2][256 * 64];   // 64 KB
  __shared__ unsigned short Bgl[2][128 * 64];  // 32 KB
  __shared__ unsigned short Bul[2][128 * 64];  // 32 KB
  int ntm = tpfx[EE];
  int ntiles = ntm * 22;
  int flat = blockIdx.x;                       // flat = nb*ntm + mt (mt fastest)
  if (flat >= ntiles) return;
  int tid = threadIdx.x, wv = tid >> 6, lane = tid & 63;
  int wm = wv >> 1, wn = wv & 1;

  // per-lane constant staging offsets
  int rA_[4], cA8_[4];
  unsigned short* dA[4];
#pragma unroll
  for (int i = 0; i < 4; ++i) {
    int g = (wv << 2) + i;
    int p = (g << 6) + lane;
    rA_[i] = p >> 3; cA8_[i] = ((p & 7) ^ (rA_[i] & 7)) << 3;
    dA[i] = &Al[0][(size_t)g << 9];
  }
  int nB_[2], cB8_[2];
  unsigned short* dG[2]; unsigned short* dU[2];
#pragma unroll
  for (int i = 0; i < 2; ++i) {
    int g = (wv << 1) + i;
    int p = (g << 6) + lane;
    nB_[i] = p >> 3; cB8_[i] = ((p & 7) ^ (nB_[i] & 7)) << 3;
    dG[i] = &Bgl[0][(size_t)g << 9];
    dU[i] = &Bul[0][(size_t)g << 9];
  }

  // current tile params + stage pointers (point at next chunk to ISSUE)
  int mt = flat % ntm, nb = flat / ntm;
  int e = 0;
  while (mt >= tpfx[e + 1]) ++e;
  size_t row0 = (size_t)mt << 8;
  int n0 = nb << 7;
  const unsigned short* sA[4]; const unsigned short* sG[2]; const unsigned short* sU[2];
#pragma unroll
  for (int i = 0; i < 4; ++i) sA[i] = Xg + (row0 + rA_[i]) * DD + cA8_[i];
  {
    const unsigned short* wgE = wgT + (size_t)e * DD * HH;
    const unsigned short* wuE = wuT + (size_t)e * DD * HH;
#pragma unroll
    for (int i = 0; i < 2; ++i) {
      int ng = n0 + nB_[i]; if (ng >= HH) ng = HH - 1;
      sG[i] = wgE + (size_t)ng * DD + cB8_[i];
      sU[i] = wuE + (size_t)ng * DD + cB8_[i];
    }
  }

  f32x4 zf = {0.f, 0.f, 0.f, 0.f};
  f32x4 ag[4][4], au[4][4];
#pragma unroll
  for (int i = 0; i < 4; ++i)
#pragma unroll
    for (int j = 0; j < 4; ++j) { ag[i][j] = zf; au[i][j] = zf; }

  // prologue: stage K-tile 0 (S0:A01, S1:A23, S2:Bg, S3:Bu)
  gload_lds16(sA[0], dA[0]); sA[0] += 64;
  gload_lds16(sA[1], dA[1]); sA[1] += 64;
  gload_lds16(sA[2], dA[2]); sA[2] += 64;
  gload_lds16(sA[3], dA[3]); sA[3] += 64;
  gload_lds16(sG[0], dG[0]); sG[0] += 64;
  gload_lds16(sG[1], dG[1]); sG[1] += 64;
  gload_lds16(sU[0], dU[0]); sU[0] += 64;
  gload_lds16(sU[1], dU[1]); sU[1] += 64;
  VMCNT2;            // S0-S2 done (Bu may lag until P0's wait)
  SCHED0; SBAR;

  size_t rowNxt = 0; int n0Nxt = 0;
  for (;;) {   // tiles
    bool hasNext = (flat + NBLK < ntiles);
    for (int kt = 0; kt < 16; ++kt) {
      bool lastG = (!hasNext) && (kt == 15);
      if (kt == 15 && hasNext) {
        // rebase stage pointers to next tile (kt'=0)
        int fN = flat + NBLK;
        int mtN = fN % ntm, nbN = fN / ntm;
        int eN = 0;
        while (mtN >= tpfx[eN + 1]) ++eN;
        rowNxt = (size_t)mtN << 8; n0Nxt = nbN << 7;
#pragma unroll
        for (int i = 0; i < 4; ++i) sA[i] = Xg + (rowNxt + rA_[i]) * DD + cA8_[i];
        const unsigned short* wgE = wgT + (size_t)eN * DD * HH;
        const unsigned short* wuE = wuT + (size_t)eN * DD * HH;
#pragma unroll
        for (int i = 0; i < 2; ++i) {
          int ng = n0Nxt + nB_[i]; if (ng >= HH) ng = HH - 1;
          sG[i] = wgE + (size_t)ng * DD + cB8_[i];
          sU[i] = wuE + (size_t)ng * DD + cB8_[i];
        }
      }
      int cur = kt & 1, wb = cur ^ 1;
      const unsigned short* alb  = &Al[0][0]  + ((size_t)cur << 14);
      const unsigned short* bglb = &Bgl[0][0] + ((size_t)cur << 13);
      const unsigned short* bulb = &Bul[0][0] + ((size_t)cur << 13);
      s16x8 af[4], bg[4], bu[4];
      // ===== P0: ks0 gate =====
#pragma unroll
      for (int fm = 0; fm < 4; ++fm) {
        int r = (wm << 6) + (fm << 4) + (lane & 15);
        af[fm] = *(const s16x8*)(alb + (r << 6) + (((lane >> 4) ^ (r & 7)) << 3));
      }
#pragma unroll
      for (int fn = 0; fn < 4; ++fn) {
        int n = (wn << 6) + (fn << 4) + (lane & 15);
        bg[fn] = *(const s16x8*)(bglb + (n << 6) + (((lane >> 4) ^ (n & 7)) << 3));
      }
      if (!lastG) {
        gload_lds16(sA[0], dA[0] + ((size_t)wb << 14)); sA[0] += 64;
        gload_lds16(sA[1], dA[1] + ((size_t)wb << 14)); sA[1] += 64;
        VMCNT2;   // retire S3(kt): Bu becomes readable after barrier
      } else {
        VMCNT0;
      }
      SCHED0; SBAR;
      LGKM0; SCHED0;
      __builtin_amdgcn_s_setprio(1);
#pragma unroll
      for (int fm = 0; fm < 4; ++fm)
#pragma unroll
        for (int fn = 0; fn < 4; ++fn)
          ag[fm][fn] = __builtin_amdgcn_mfma_f32_16x16x32_bf16(af[fm], bg[fn], ag[fm][fn], 0, 0, 0);
      __builtin_amdgcn_s_setprio(0);
      SBAR;
      // ===== P1: ks0 up =====
#pragma unroll
      for (int fn = 0; fn < 4; ++fn) {
        int n = (wn << 6) + (fn << 4) + (lane & 15);
        bu[fn] = *(const s16x8*)(bulb + (n << 6) + (((lane >> 4) ^ (n & 7)) << 3));
      }
      if (!lastG) {
        gload_lds16(sA[2], dA[2] + ((size_t)wb << 14)); sA[2] += 64;
        gload_lds16(sA[3], dA[3] + ((size_t)wb << 14)); sA[3] += 64;
      }
      SCHED0; SBAR;
      LGKM0; SCHED0;
      __builtin_amdgcn_s_setprio(1);
#pragma unroll
      for (int fm = 0; fm < 4; ++fm)
#pragma unroll
        for (int fn = 0; fn < 4; ++fn)
          au[fm][fn] = __builtin_amdgcn_mfma_f32_16x16x32_bf16(af[fm], bu[fn], au[fm][fn], 0, 0, 0);
      __builtin_amdgcn_s_setprio(0);
      SBAR;
      // ===== P2: ks1 gate =====
#pragma unroll
      for (int fm = 0; fm < 4; ++fm) {
        int r = (wm << 6) + (fm << 4) + (lane & 15);
        af[fm] = *(const s16x8*)(alb + (r << 6) + (((4 + (lane >> 4)) ^ (r & 7)) << 3));
      }
#pragma unroll
      for (int fn = 0; fn < 4; ++fn) {
        int n = (wn << 6) + (fn << 4) + (lane & 15);
        bg[fn] = *(const s16x8*)(bglb + (n << 6) + (((4 + (lane >> 4)) ^ (n & 7)) << 3));
      }
      if (!lastG) {
        gload_lds16(sG[0], dG[0] + ((size_t)wb << 13)); sG[0] += 64;
        gload_lds16(sG[1], dG[1] + ((size_t)wb << 13)); sG[1] += 64;
      }
      SCHED0; SBAR;
      LGKM0; SCHED0;
      __builtin_amdgcn_s_setprio(1);
#pragma unroll
      for (int fm = 0; fm < 4; ++fm)
#pragma unroll
        for (int fn = 0; fn < 4; ++fn)
          ag[fm][fn] = __builtin_amdgcn_mfma_f32_16x16x32_bf16(af[fm], bg[fn], ag[fm][fn], 0, 0, 0);
      __builtin_amdgcn_s_setprio(0);
      SBAR;
      // ===== P3: ks1 up =====
#pragma unroll
      for (int fn = 0; fn < 4; ++fn) {
        int n = (wn << 6) + (fn << 4) + (lane & 15);
        bu[fn] = *(const s16x8*)(bulb + (n << 6) + (((4 + (lane >> 4)) ^ (n & 7)) << 3));
      }
      if (!lastG) {
        gload_lds16(sU[0], dU[0] + ((size_t)wb << 13)); sU[0] += 64;
        gload_lds16(sU[1], dU[1] + ((size_t)wb << 13)); sU[1] += 64;
        VMCNT2;   // retire next K-step's S0-S2 (A+Bg)
      }
      SCHED0; SBAR;
      LGKM0; SCHED0;
      __builtin_amdgcn_s_setprio(1);
#pragma unroll
      for (int fm = 0; fm < 4; ++fm)
#pragma unroll
        for (int fn = 0; fn < 4; ++fn)
          au[fm][fn] = __builtin_amdgcn_mfma_f32_16x16x32_bf16(af[fm], bu[fn], au[fm][fn], 0, 0, 0);
      __builtin_amdgcn_s_setprio(0);
      SBAR;
    }
    // epilogue tile (row0, n0): silu(g)*u -> bf16 (overlaps next tile's loads)
#pragma unroll
    for (int fm = 0; fm < 4; ++fm)
#pragma unroll
      for (int fn = 0; fn < 4; ++fn)
#pragma unroll
        for (int j = 0; j < 4; ++j) {
          int cc = n0 + (wn << 6) + (fn << 4) + (lane & 15);
          if (cc < HH) {
            float gv = ag[fm][fn][j];
            float uv = au[fm][fn][j];
            float hv = gv / (1.f + __expf(-gv)) * uv;
            int r = (wm << 6) + (fm << 4) + ((lane >> 4) << 2) + j;
            hbuf[(row0 + r) * HH + (size_t)cc] = (unsigned short)f2bf1(hv);
          }
          ag[fm][fn][j] = 0.f; au[fm][fn][j] = 0.f;
        }
    if (!hasNext) break;
    row0 = rowNxt; n0 = n0Nxt;
    flat += NBLK;
  }
}

// ---------------- FC2: persistent blocks, continuous 2-phase pipeline ----------------
// tile 256M x 128N x 64K; 8 waves; A dbuf, B triple-buffer (staged 2 ahead)
__global__ __launch_bounds__(512, 1) void k_fc2t(
    const unsigned short* __restrict__ hbuf, const unsigned short* __restrict__ wdT,
    const int* __restrict__ cnt, const int* __restrict__ tpfx,
    const int* __restrict__ tok, const float* __restrict__ wgt,
    float* __restrict__ out) {
  __shared__ unsigned short Al[2][256 * 64];   // 64 KB
  __shared__ unsigned short Bl[3][128 * 64];   // 48 KB
  int ntm = tpfx[EE];
  int ntiles = ntm * 8;
  int flat = blockIdx.x;                       // flat = nb*ntm + mt
  if (flat >= ntiles) return;
  int tid = threadIdx.x, wv = tid >> 6, lane = tid & 63;
  int wm = wv >> 1, wn = wv & 1;

  int rA_[4], cA8_[4];
  unsigned short* dA[4];
#pragma unroll
  for (int i = 0; i < 4; ++i) {
    int g = (wv << 2) + i;
    int p = (g << 6) + lane;
    rA_[i] = p >> 3; cA8_[i] = ((p & 7) ^ (rA_[i] & 7)) << 3;
    dA[i] = &Al[0][(size_t)g << 9];
  }
  int nB_[2], cB8_[2];
  unsigned short* dB[2];
#pragma unroll
  for (int i = 0; i < 2; ++i) {
    int g = (wv << 1) + i;
    int p = (g << 6) + lane;
    nB_[i] = p >> 3; cB8_[i] = ((p & 7) ^ (nB_[i] & 7)) << 3;
    dB[i] = &Bl[0][(size_t)g << 9];
  }

  int mt = flat % ntm, nb = flat / ntm;
  int e = 0;
  while (mt >= tpfx[e + 1]) ++e;
  size_t row0 = (size_t)mt << 8;
  int n0 = nb << 7;
  int mrem = cnt[e] - ((mt - tpfx[e]) << 8);
  if (mrem > 256) mrem = 256;
  const unsigned short* sA[4]; const unsigned short* sB[2];
#pragma unroll
  for (int i = 0; i < 4; ++i) sA[i] = hbuf + (row0 + rA_[i]) * HH + cA8_[i];
  {
    const unsigned short* wdE = wdT + (size_t)e * DD * HH;
#pragma unroll
    for (int i = 0; i < 2; ++i) sB[i] = wdE + (size_t)(n0 + nB_[i]) * HH + cB8_[i];
  }

  f32x4 zf = {0.f, 0.f, 0.f, 0.f};
  f32x4 acc[4][4];
#pragma unroll
  for (int i = 0; i < 4; ++i)
#pragma unroll
    for (int j = 0; j < 4; ++j) acc[i][j] = zf;

  // prologue: B(0)->slot0, A(0)->buf0, B(1)->slot1
  gload_lds16(sB[0], dB[0]); sB[0] += 64;
  gload_lds16(sB[1], dB[1]); sB[1] += 64;
  gload_lds16(sA[0], dA[0]); sA[0] += 64;
  gload_lds16(sA[1], dA[1]); sA[1] += 64;
  gload_lds16(sA[2], dA[2]); sA[2] += 64;
  gload_lds16(sA[3], dA[3]); sA[3] += 64;
  gload_lds16(sB[0], dB[0] + 8192); sB[0] += 64;
  gload_lds16(sB[1], dB[1] + 8192); sB[1] += 64;
  VMCNT2;     // B(0)+A(0) done; B(1) in flight
  SCHED0; SBAR;

  size_t rowNxt = 0; int n0Nxt = 0, mremNxt = 0;
  const unsigned short* wdENxt = wdT;
  int curA = 0, ib = 0;                        // A parity, B consume slot
  for (;;) {
    bool hasNext = (flat + NBLK < ntiles);
    for (int kt = 0; kt < 43; ++kt) {
      bool endA = (!hasNext) && (kt == 42);    // no A issue
      bool endB = (!hasNext) && (kt >= 41);    // no B issue
      if (hasNext && kt == 41) {
        // next-tile params + B rebase (B staged 2 ahead crosses boundary first)
        int fN = flat + NBLK;
        int mtN = fN % ntm, nbN = fN / ntm;
        int eN = 0;
        while (mtN >= tpfx[eN + 1]) ++eN;
        rowNxt = (size_t)mtN << 8; n0Nxt = nbN << 7;
        mremNxt = cnt[eN] - ((mtN - tpfx[eN]) << 8);
        if (mremNxt > 256) mremNxt = 256;
        wdENxt = wdT + (size_t)eN * DD * HH;
#pragma unroll
        for (int i = 0; i < 2; ++i) sB[i] = wdENxt + (size_t)(n0Nxt + nB_[i]) * HH + cB8_[i];
      }
      if (hasNext && kt == 42) {
#pragma unroll
        for (int i = 0; i < 4; ++i) sA[i] = hbuf + (rowNxt + rA_[i]) * HH + cA8_[i];
      }
      int wbA = curA ^ 1;
      int ibw = (ib >= 1) ? ib - 1 : 2;        // (ib+2)%3
      const unsigned short* alb = &Al[0][0] + ((size_t)curA << 14);
      const unsigned short* blb = &Bl[0][0] + (size_t)ib * 8192;
      s16x8 af[4], bf[4];
      // ===== P0: ks0 =====
#pragma unroll
      for (int fm = 0; fm < 4; ++fm) {
        int r = (wm << 6) + (fm << 4) + (lane & 15);
        af[fm] = *(const s16x8*)(alb + (r << 6) + (((lane >> 4) ^ (r & 7)) << 3));
      }
#pragma unroll
      for (int fn = 0; fn < 4; ++fn) {
        int n = (wn << 6) + (fn << 4) + (lane & 15);
        bf[fn] = *(const s16x8*)(blb + (n << 6) + (((lane >> 4) ^ (n & 7)) << 3));
      }
      if (!endA) {
        gload_lds16(sA[0], dA[0] + ((size_t)wbA << 14)); sA[0] += 64;
        gload_lds16(sA[1], dA[1] + ((size_t)wbA << 14)); sA[1] += 64;
        gload_lds16(sA[2], dA[2] + ((size_t)wbA << 14)); sA[2] += 64;
        gload_lds16(sA[3], dA[3] + ((size_t)wbA << 14)); sA[3] += 64;
      }
      SCHED0; SBAR;
      LGKM0; SCHED0;
      __builtin_amdgcn_s_setprio(1);
#pragma unroll
      for (int fm = 0; fm < 4; ++fm)
#pragma unroll
        for (int fn = 0; fn < 4; ++fn)
          acc[fm][fn] = __builtin_amdgcn_mfma_f32_16x16x32_bf16(af[fm], bf[fn], acc[fm][fn], 0, 0, 0);
      __builtin_amdgcn_s_setprio(0);
      SBAR;
      // ===== P1: ks1 =====
#pragma unroll
      for (int fm = 0; fm < 4; ++fm) {
        int r = (wm << 6) + (fm << 4) + (lane & 15);
        af[fm] = *(const s16x8*)(alb + (r << 6) + (((4 + (lane >> 4)) ^ (r & 7)) << 3));
      }
#pragma unroll
      for (int fn = 0; fn < 4; ++fn) {
        int n = (wn << 6) + (fn << 4) + (lane & 15);
        bf[fn] = *(const s16x8*)(blb + (n << 6) + (((4 + (lane >> 4)) ^ (n & 7)) << 3));
      }
      if (!endB) {
        gload_lds16(sB[0], dB[0] + (size_t)ibw * 8192); sB[0] += 64;
        gload_lds16(sB[1], dB[1] + (size_t)ibw * 8192); sB[1] += 64;
      }
      if (endB) { VMCNT0; } else { VMCNT2; }   // retire next K-step's A+B
      SCHED0; SBAR;
      LGKM0; SCHED0;
      __builtin_amdgcn_s_setprio(1);
#pragma unroll
      for (int fm = 0; fm < 4; ++fm)
#pragma unroll
        for (int fn = 0; fn < 4; ++fn)
          acc[fm][fn] = __builtin_amdgcn_mfma_f32_16x16x32_bf16(af[fm], bf[fn], acc[fm][fn], 0, 0, 0);
      __builtin_amdgcn_s_setprio(0);
      SBAR;
      curA ^= 1;
      ib = (ib >= 2) ? 0 : ib + 1;
    }
    // epilogue: weighted scatter-add (overlaps next tile's loads)
#pragma unroll
    for (int fm = 0; fm < 4; ++fm)
#pragma unroll
      for (int j = 0; j < 4; ++j) {
        int r = (wm << 6) + (fm << 4) + ((lane >> 4) << 2) + j;
        if (r < mrem) {
          int tk = tok[row0 + r];
          float cw = wgt[row0 + r];
          float* ob = out + (size_t)tk * DD + (size_t)(n0 + (wn << 6) + (lane & 15));
#pragma unroll
          for (int fn = 0; fn < 4; ++fn)
            atomicAdd(ob + (fn << 4), acc[fm][fn][j] * cw);
        }
#pragma unroll
        for (int fn = 0; fn < 4; ++fn) acc[fm][fn][j] = 0.f;
      }
    if (!hasNext) break;
    row0 = rowNxt; n0 = n0Nxt; mrem = mremNxt;
    flat += NBLK;
  }
}

// ================= fallback kernels (128-row tiles over 256-aligned segments) =================
__global__ __launch_bounds__(256) void k_fc1_cv(
    const unsigned short* __restrict__ Xg, const float* __restrict__ wg,
    const float* __restrict__ wu, const int* __restrict__ tpfx,
    unsigned short* __restrict__ hbuf) {
  __shared__ unsigned short Al[128 * 64];
  __shared__ unsigned short Bgl[64 * 64];
  __shared__ unsigned short Bul[64 * 64];
  int mt = blockIdx.x;
  if (mt >= 2 * tpfx[EE]) return;
  int e = 0;
  while (mt >= 2 * tpfx[e + 1]) ++e;
  int n0 = blockIdx.y << 6;
  size_t row0 = (size_t)mt << 7;
  const float* wge = wg + (size_t)e * DD * HH;
  const float* wue = wu + (size_t)e * DD * HH;
  int tid = threadIdx.x, wv = tid >> 6, lane = tid & 63;
  int wm = wv >> 1, wn = wv & 1;
  f32x4 zf = {0.f, 0.f, 0.f, 0.f};
  f32x4 ag[4][2], au[4][2];
#pragma unroll
  for (int i = 0; i < 4; ++i)
#pragma unroll
    for (int j = 0; j < 2; ++j) { ag[i][j] = zf; au[i][j] = zf; }
  for (int kt = 0; kt < DD / 64; ++kt) {
    int k0 = kt << 6;
#pragma unroll
    for (int i = 0; i < 4; ++i) {
      int g = (wv << 2) + i;
      int p = (g << 6) + lane;
      int r = p >> 3, c = (p & 7) ^ (r & 7);
      gload_lds16(Xg + (row0 + r) * DD + (size_t)(k0 + (c << 3)), Al + ((size_t)g << 9));
    }
#pragma unroll
    for (int a2 = 0; a2 < 2; ++a2) {
      int idx = tid + (a2 << 8);
      int kk = (idx >> 4) << 1;
      int nn = (idx & 15) << 2;
      const float* pg = wge + (size_t)(k0 + kk) * HH + (n0 + nn);
      const float* pu = wue + (size_t)(k0 + kk) * HH + (n0 + nn);
      float4 g0 = *(const float4*)pg;
      float4 g1 = *(const float4*)(pg + HH);
      float4 u0 = *(const float4*)pu;
      float4 u1 = *(const float4*)(pu + HH);
      const float* g0f = (const float*)&g0; const float* g1f = (const float*)&g1;
      const float* u0f = (const float*)&u0; const float* u1f = (const float*)&u1;
      int kb = kk << 1, ch = kb >> 4, inb = kb & 15;
#pragma unroll
      for (int j = 0; j < 4; ++j) {
        int n = nn + j;
        int off = (n << 7) + ((ch ^ bswz(n)) << 4) + inb;
        *(unsigned int*)((char*)Bgl + off) = f2bf2(g0f[j], g1f[j]);
        *(unsigned int*)((char*)Bul + off) = f2bf2(u0f[j], u1f[j]);
      }
    }
    __syncthreads();
#pragma unroll
    for (int ks = 0; ks < 2; ++ks) {
      int cch = (ks << 2) + (lane >> 4);
      s16x8 af[4];
#pragma unroll
      for (int fm = 0; fm < 4; ++fm) {
        int r = (wm << 6) + (fm << 4) + (lane & 15);
        af[fm] = *(const s16x8*)(Al + (r << 6) + ((cch ^ (r & 7)) << 3));
      }
      s16x8 bg[2], bu[2];
#pragma unroll
      for (int fn = 0; fn < 2; ++fn) {
        int n = (wn << 5) + (fn << 4) + (lane & 15);
        int o = (n << 6) + ((cch ^ bswz(n)) << 3);
        bg[fn] = *(const s16x8*)(Bgl + o);
        bu[fn] = *(const s16x8*)(Bul + o);
      }
#pragma unroll
      for (int fm = 0; fm < 4; ++fm)
#pragma unroll
        for (int fn = 0; fn < 2; ++fn) {
          ag[fm][fn] = __builtin_amdgcn_mfma_f32_16x16x32_bf16(af[fm], bg[fn], ag[fm][fn], 0, 0, 0);
          au[fm][fn] = __builtin_amdgcn_mfma_f32_16x16x32_bf16(af[fm], bu[fn], au[fm][fn], 0, 0, 0);
        }
    }
    __syncthreads();
  }
#pragma unroll
  for (int fm = 0; fm < 4; ++fm)
#pragma unroll
    for (int fn = 0; fn < 2; ++fn)
#pragma unroll
      for (int j = 0; j < 4; ++j) {
        float gv = ag[fm][fn][j];
        float uv = au[fm][fn][j];
        float hv = gv / (1.f + __expf(-gv)) * uv;
        int r = (wm << 6) + (fm << 4) + ((lane >> 4) << 2) + j;
        int cc = (wn << 5) + (fn << 4) + (lane & 15);
        hbuf[(row0 + r) * HH + (size_t)(n0 + cc)] = (unsigned short)f2bf1(hv);
      }
}

__global__ __launch_bounds__(256) void k_fc2_cv(
    const unsigned short* __restrict__ hbuf, const float* __restrict__ wd,
    const int* __restrict__ cnt, const int* __restrict__ tpfx,
    const int* __restrict__ tok, const float* __restrict__ wgt,
    float* __restrict__ out) {
  __shared__ unsigned short Al[128 * 64];
  __shared__ unsigned short Bl[128 * 64];
  int mt = blockIdx.x;
  if (mt >= 2 * tpfx[EE]) return;
  int e = 0;
  while (mt >= 2 * tpfx[e + 1]) ++e;
  int n0 = blockIdx.y << 7;
  size_t row0 = (size_t)mt << 7;
  int mrem = cnt[e] - ((mt - 2 * tpfx[e]) << 7);
  if (mrem > 128) mrem = 128;
  const float* wde = wd + (size_t)e * HH * DD;
  int tid = threadIdx.x, wv = tid >> 6, lane = tid & 63;
  int wm = wv >> 1, wn = wv & 1;
  f32x4 zf = {0.f, 0.f, 0.f, 0.f};
  f32x4 acc[4][4];
#pragma unroll
  for (int i = 0; i < 4; ++i)
#pragma unroll
    for (int j = 0; j < 4; ++j) acc[i][j] = zf;
  for (int kt = 0; kt < HH / 64; ++kt) {
    int k0 = kt << 6;
#pragma unroll
    for (int i = 0; i < 4; ++i) {
      int g = (wv << 2) + i;
      int p = (g << 6) + lane;
      int r = p >> 3, c = (p & 7) ^ (r & 7);
      gload_lds16(hbuf + (row0 + r) * HH + (size_t)(k0 + (c << 3)), Al + ((size_t)g << 9));
    }
#pragma unroll
    for (int a2 = 0; a2 < 4; ++a2) {
      int idx = tid + (a2 << 8);
      int kk = (idx >> 5) << 1;
      int nn = (idx & 31) << 2;
      const float* pb = wde + (size_t)(k0 + kk) * DD + (n0 + nn);
      float4 b0 = *(const float4*)pb;
      float4 b1 = *(const float4*)(pb + DD);
      const float* b0f = (const float*)&b0;
      const float* b1f = (const float*)&b1;
      int kb = kk << 1, ch = kb >> 4, inb = kb & 15;
#pragma unroll
      for (int j = 0; j < 4; ++j) {
        int n = nn + j;
        int off = (n << 7) + ((ch ^ bswz(n)) << 4) + inb;
        *(unsigned int*)((char*)Bl + off) = f2bf2(b0f[j], b1f[j]);
      }
    }
    __syncthreads();
#pragma unroll
    for (int ks = 0; ks < 2; ++ks) {
      int cch = (ks << 2) + (lane >> 4);
      s16x8 af[4], bf[4];
#pragma unroll
      for (int fm = 0; fm < 4; ++fm) {
        int r = (wm << 6) + (fm << 4) + (lane & 15);
        af[fm] = *(const s16x8*)(Al + (r << 6) + ((cch ^ (r & 7)) << 3));
      }
#pragma unroll
      for (int fn = 0; fn < 4; ++fn) {
        int n = (wn << 6) + (fn << 4) + (lane & 15);
        bf[fn] = *(const s16x8*)(Bl + (n << 6) + ((cch ^ bswz(n)) << 3));
      }
#pragma unroll
      for (int fm = 0; fm < 4; ++fm)
#pragma unroll
        for (int fn = 0; fn < 4; ++fn)
          acc[fm][fn] = __builtin_amdgcn_mfma_f32_16x16x32_bf16(af[fm], bf[fn], acc[fm][fn], 0, 0, 0);
    }
    __syncthreads();
  }
#pragma unroll
  for (int fm = 0; fm < 4; ++fm)
#pragma unroll
    for (int j = 0; j < 4; ++j) {
      int r = (wm << 6) + (fm << 4) + ((lane >> 4) << 2) + j;
      if (r < mrem) {
        int tk = tok[row0 + r];
        float cw = wgt[row0 + r];
        float* ob = out + (size_t)tk * DD + (size_t)(n0 + (wn << 6) + (lane & 15));
#pragma unroll
        for (int fn = 0; fn < 4; ++fn)
          atomicAdd(ob + (fn << 4), acc[fm][fn][j] * cw);
      }
    }
}

extern "C" void kernel_launch(void* const* d_in, const int* in_sizes, int n_in,
                              void* d_out, int out_size, void* d_ws, size_t ws_size,
                              hipStream_t stream) {
  const float* x  = (const float*)d_in[0];
  const float* rw = (const float*)d_in[1];
  const float* wg = (const float*)d_in[2];
  const float* wu = (const float*)d_in[3];
  const float* wd = (const float*)d_in[4];
  float* out = (float*)d_out;

  // workspace layout (256-row padded segments; max 18432 gathered rows)
  char* w = (char*)d_ws;
  int* cnt    = (int*)(w + 0);
  int* cursor = (int*)(w + 32);
  int* tpfx   = (int*)(w + 64);
  int* topi   = (int*)(w + 256);                      // 16384 ints
  float* topw = (float*)(w + 65792);                  // 16384 f32
  int* tok    = (int*)(w + 131328);                   // 18432 ints
  float* wgt  = (float*)(w + 205056);                 // 18432 f32
  unsigned short* Xg  = (unsigned short*)(w + 278784);        // 37,748,736 B
  unsigned short* hb  = (unsigned short*)(w + 38027520ULL);   // 101,449,728 B
  unsigned short* wgT = (unsigned short*)(w + 139477248ULL);  // 45,088,768 B
  unsigned short* wuT = (unsigned short*)(w + 184566016ULL);  // 45,088,768 B
  unsigned short* wdT = wgT;  // reuses wgT slot AFTER fc1
  const size_t NEED = 229654784ULL;

  hipMemsetAsync(d_out, 0, (size_t)T_TOKENS * DD * sizeof(float), stream);
  k_init<<<1, 64, 0, stream>>>(cursor);
  k_router<<<T_TOKENS / 4, 256, 0, stream>>>(x, rw, topi, topw);
  k_assign<<<T_TOKENS / 256, 256, 0, stream>>>(topi, cursor);
  k_offsets<<<1, 64, 0, stream>>>(cursor, cnt, tpfx);
  k_copy<<<T_TOKENS / 4, 256, 0, stream>>>(x, topi, topw, tpfx, tok, wgt, Xg);
  k_padzero<<<512, 256, 0, stream>>>(cnt, tpfx, Xg);

  if (ws_size >= NEED) {
    k_wtrans<<<EE * 16 * 43, 256, 0, stream>>>(wg, wgT, DD, HH);
    k_wtrans<<<EE * 16 * 43, 256, 0, stream>>>(wu, wuT, DD, HH);
    k_fc1t<<<NBLK, 512, 0, stream>>>(Xg, wgT, wuT, tpfx, hb);
    k_wtrans<<<EE * 43 * 16, 256, 0, stream>>>(wd, wdT, HH, DD);  // over wgT slot
    k_fc2t<<<NBLK, 512, 0, stream>>>(hb, wdT, cnt, tpfx, tok, wgt, out);
  } else {
    k_fc1_cv<<<dim3(MT1, HH / 64), 256, 0, stream>>>(Xg, wg, wu, tpfx, hb);
    k_fc2_cv<<<dim3(MT1, DD / 128), 256, 0, stream>>>(hb, wd, cnt, tpfx, tok, wgt, out);
  }
}

// Round 8
// 567.750 us; speedup vs baseline: 1.2753x; 1.0035x over previous
//
#include <hip/hip_runtime.h>
#include <hip/hip_bf16.h>
#include <math.h>

// Problem constants
#define T_TOKENS 8192      // B*S
#define DD 1024            // embed dim
#define HH 2752            // swiglu hidden (43*64)
#define EE 8               // experts
#define NBLK 256           // persistent blocks (1 per CU)
#define MT1 144            // 128-row tiles (fallback kernels)
#define NRB 2048           // router blocks in k_prep
#define ZB 2048            // out-zero blocks in k_prep
#define NTB 5504           // transpose tiles per weight tensor (8*16*43)

typedef __attribute__((ext_vector_type(8))) short s16x8;
typedef __attribute__((ext_vector_type(4))) float f32x4;

#define VMCNT0 asm volatile("s_waitcnt vmcnt(0)" ::: "memory")
#define VMCNT2 asm volatile("s_waitcnt vmcnt(2)" ::: "memory")
#define LGKM0  asm volatile("s_waitcnt lgkmcnt(0)" ::: "memory")
#define SBAR   __builtin_amdgcn_s_barrier()
#define SCHED0 __builtin_amdgcn_sched_barrier(0)

__device__ __forceinline__ unsigned int f2bf1(float f) {
  unsigned int u = __float_as_uint(f);
  return (u + 0x7FFFu + ((u >> 16) & 1u)) >> 16;   // RNE fp32->bf16
}
__device__ __forceinline__ unsigned int f2bf2(float lo, float hi) {
  return f2bf1(lo) | (f2bf1(hi) << 16);
}

__device__ __forceinline__ void gload_lds16(const void* g, void* l) {
  __builtin_amdgcn_global_load_lds((const __attribute__((address_space(1))) void*)g,
                                   (__attribute__((address_space(3))) void*)l, 16, 0, 0);
}

// legacy B-tile swizzle (fallback kernels only)
__device__ __forceinline__ int bswz(int n) {
  return ((n >> 2) & 7) ^ ((n & 3) << 1);
}

// ---- transpose+convert one 64x64 tile: fp32 [R][C] -> bf16 [C][R] ----
__device__ __forceinline__ void trans_tile(const float* __restrict__ src,
                                           unsigned short* __restrict__ dst,
                                           int R, int C, int gt, unsigned int* Lt) {
  int ctn = C >> 6;
  int tiles = (R >> 6) * ctn;
  int e = gt / tiles, t = gt % tiles;
  int rt0 = (t / ctn) << 6, ct0 = (t % ctn) << 6;
  const float* s = src + (size_t)e * R * C;
  unsigned short* d = dst + (size_t)e * R * C;
  int tid = threadIdx.x;
  int rp = tid >> 3, cg = tid & 7;
  const float* p0 = s + (size_t)(rt0 + (rp << 1)) * C + ct0 + (cg << 3);
  float4 a0 = *(const float4*)p0;
  float4 a1 = *(const float4*)(p0 + 4);
  float4 b0 = *(const float4*)(p0 + C);
  float4 b1 = *(const float4*)(p0 + C + 4);
  float va[8] = {a0.x, a0.y, a0.z, a0.w, a1.x, a1.y, a1.z, a1.w};
  float vb[8] = {b0.x, b0.y, b0.z, b0.w, b1.x, b1.y, b1.z, b1.w};
#pragma unroll
  for (int j = 0; j < 8; ++j)
    Lt[((cg << 3) + j) * 33 + rp] = f2bf2(va[j], vb[j]);
  __syncthreads();
  int c = tid >> 2, q = tid & 3;
  unsigned int o[8];
#pragma unroll
  for (int i = 0; i < 8; ++i) o[i] = Lt[c * 33 + (q << 3) + i];
  unsigned short* pd = d + (size_t)(ct0 + c) * R + rt0 + (q << 4);
  *(uint4*)pd       = make_uint4(o[0], o[1], o[2], o[3]);
  *(uint4*)(pd + 8) = make_uint4(o[4], o[5], o[6], o[7]);
}

// ---------------- fused prep: router + out-zero + weight transposes + cursor init ----------------
// grid = NRB + ZB + {0,2,3}*NTB blocks of 256 threads
__global__ __launch_bounds__(256) void k_prep(
    const float* __restrict__ x, const float* __restrict__ rw,
    int* __restrict__ topi, float* __restrict__ topw, int* __restrict__ cursor,
    float* __restrict__ outz,
    const float* __restrict__ wg, unsigned short* __restrict__ wgT,
    const float* __restrict__ wu, unsigned short* __restrict__ wuT,
    const float* __restrict__ wd, unsigned short* __restrict__ wdT) {
  __shared__ unsigned int Lt[64 * 33];
  int bid = blockIdx.x;
  if (bid == 0 && threadIdx.x < EE) cursor[threadIdx.x] = 0;
  if (bid < NRB) {
    // ---- router: 4 tokens per block, fp64 logits -> top2 ----
    int t = (bid * 256 + threadIdx.x) >> 6;
    int lane = threadIdx.x & 63;
    const float* xr = x + (size_t)t * DD;
    double acc[EE];
#pragma unroll
    for (int e = 0; e < EE; ++e) acc[e] = 0.0;
#pragma unroll
    for (int i = 0; i < DD / 64; ++i) {
      int d = lane + (i << 6);
      double xv = (double)xr[d];
      const float4* rp = (const float4*)(rw + (size_t)d * EE);
      float4 r0 = rp[0], r1 = rp[1];
      acc[0] += xv * (double)r0.x; acc[1] += xv * (double)r0.y;
      acc[2] += xv * (double)r0.z; acc[3] += xv * (double)r0.w;
      acc[4] += xv * (double)r1.x; acc[5] += xv * (double)r1.y;
      acc[6] += xv * (double)r1.z; acc[7] += xv * (double)r1.w;
    }
#pragma unroll
    for (int e = 0; e < EE; ++e) {
      double v = acc[e];
#pragma unroll
      for (int off = 32; off > 0; off >>= 1) v += __shfl_down(v, off, 64);
      acc[e] = v;
    }
    if (lane == 0) {
      int i1 = 0; double l1 = acc[0];
#pragma unroll
      for (int e = 1; e < EE; ++e) if (acc[e] > l1) { l1 = acc[e]; i1 = e; }
      int i2 = -1; double l2 = -1e300;
#pragma unroll
      for (int e = 0; e < EE; ++e) if (e != i1 && acc[e] > l2) { l2 = acc[e]; i2 = e; }
      double ee = exp(l2 - l1);
      float w1 = (float)(1.0 / (1.0 + ee));
      topi[2 * t] = i1; topi[2 * t + 1] = i2;
      topw[2 * t] = w1; topw[2 * t + 1] = 1.0f - w1;
    }
  } else if (bid < NRB + ZB) {
    // ---- zero d_out (replaces hipMemsetAsync) ----
    int idx = (bid - NRB) * 256 + threadIdx.x;        // 0..524287
    uint4 z = make_uint4(0u, 0u, 0u, 0u);
    uint4* p = (uint4*)outz;
#pragma unroll
    for (int i = 0; i < 4; ++i) p[idx + i * 524288] = z;
  } else if (bid < NRB + ZB + NTB) {
    trans_tile(wg, wgT, DD, HH, bid - NRB - ZB, Lt);
  } else if (bid < NRB + ZB + 2 * NTB) {
    trans_tile(wu, wuT, DD, HH, bid - NRB - ZB - NTB, Lt);
  } else {
    trans_tile(wd, wdT, HH, DD, bid - NRB - ZB - 2 * NTB, Lt);
  }
}

__global__ __launch_bounds__(256) void k_assign(int* __restrict__ topi,
                                                int* __restrict__ cursor) {
  __shared__ int hist[EE];
  __shared__ int base[EE];
  int t = blockIdx.x * 256 + threadIdx.x;
  if (threadIdx.x < EE) hist[threadIdx.x] = 0;
  __syncthreads();
  int e0 = topi[2 * t], e1 = topi[2 * t + 1];
  int r0 = atomicAdd(&hist[e0], 1);
  int r1 = atomicAdd(&hist[e1], 1);
  __syncthreads();
  if (threadIdx.x < EE) base[threadIdx.x] = atomicAdd(&cursor[threadIdx.x], hist[threadIdx.x]);
  __syncthreads();
  topi[2 * t]     = e0 | ((base[e0] + r0) << 3);
  topi[2 * t + 1] = e1 | ((base[e1] + r1) << 3);
}

// tpfx in 256-row tile units
__global__ void k_offsets(const int* __restrict__ cursor, int* __restrict__ cnt,
                          int* __restrict__ tpfx) {
  if (threadIdx.x == 0) {
    int acc = 0;
#pragma unroll
    for (int e = 0; e < EE; ++e) {
      cnt[e] = cursor[e];
      tpfx[e] = acc;
      acc += (cursor[e] + 255) >> 8;
    }
    tpfx[EE] = acc;
  }
}

// fused copy (blocks 0..2047) + padzero (blocks 2048..2559)
__global__ void k_copy_pad(const float* __restrict__ x, const int* __restrict__ topi,
                           const float* __restrict__ topw, const int* __restrict__ tpfx,
                           const int* __restrict__ cnt,
                           int* __restrict__ tok, float* __restrict__ wgt,
                           unsigned short* __restrict__ Xg) {
  int bid = blockIdx.x;
  int lane = threadIdx.x & 63;
  if (bid < 2048) {
    int t = (bid * 256 + threadIdx.x) >> 6;
    int v0 = topi[2 * t], v1 = topi[2 * t + 1];
    int e0 = v0 & 7, e1 = v1 & 7;
    int r0 = (tpfx[e0] << 8) + (v0 >> 3);
    int r1 = (tpfx[e1] << 8) + (v1 >> 3);
    if (lane == 0) {
      tok[r0] = t; wgt[r0] = topw[2 * t];
      tok[r1] = t; wgt[r1] = topw[2 * t + 1];
    }
    const float4* xp = (const float4*)(x + (size_t)t * DD) + (lane << 2);
    float4 a = xp[0], b = xp[1], c = xp[2], d = xp[3];
    uint4 o0, o1;
    o0.x = f2bf2(a.x, a.y); o0.y = f2bf2(a.z, a.w);
    o0.z = f2bf2(b.x, b.y); o0.w = f2bf2(b.z, b.w);
    o1.x = f2bf2(c.x, c.y); o1.y = f2bf2(c.z, c.w);
    o1.z = f2bf2(d.x, d.y); o1.w = f2bf2(d.z, d.w);
    uint4* p0 = (uint4*)(Xg + (size_t)r0 * DD) + (lane << 1);
    p0[0] = o0; p0[1] = o1;
    uint4* p1 = (uint4*)(Xg + (size_t)r1 * DD) + (lane << 1);
    p1[0] = o0; p1[1] = o1;
  } else {
    int wid = ((bid - 2048) * 256 + threadIdx.x) >> 6;
    int e = wid >> 8, i = wid & 255;
    int c = cnt[e];
    int padded = ((c + 255) >> 8) << 8;
    if (c + i < padded) {
      size_t row = ((size_t)tpfx[e] << 8) + (size_t)(c + i);
      uint4 z = make_uint4(0u, 0u, 0u, 0u);
      uint4* p = (uint4*)(Xg + row * DD) + (lane << 1);
      p[0] = z; p[1] = z;
    }
  }
}

// standalone transpose (mid-ws path: wd -> wgT slot between fc1 and fc2)
__global__ __launch_bounds__(256) void k_wtrans(const float* __restrict__ src,
                                                unsigned short* __restrict__ dst,
                                                int R, int C) {
  __shared__ unsigned int Lt[64 * 33];
  trans_tile(src, dst, R, C, blockIdx.x, Lt);
}

// ---------------- FC1: persistent blocks, continuous 4-phase pipeline ----------------
// tile 256M x 128N/mat x 64K; 8 waves (4Mx2N); wave 64x64 per matrix
__global__ __launch_bounds__(512, 1) void k_fc1t(
    const unsigned short* __restrict__ Xg, const unsigned short* __restrict__ wgT,
    const unsigned short* __restrict__ wuT, const int* __restrict__ tpfx,
    unsigned short* __restrict__ hbuf) {
  __shared__ unsigned short Al[2][256 * 64];   // 64 KB
  __shared__ unsigned short Bgl[2][128 * 64];  // 32 KB
  __shared__ unsigned short Bul[2][128 * 64];  // 32 KB
  int ntm = tpfx[EE];
  int ntiles = ntm * 22;
  int flat = blockIdx.x;                       // flat = nb*ntm + mt (mt fastest)
  if (flat >= ntiles) return;
  int tid = threadIdx.x, wv = tid >> 6, lane = tid & 63;
  int wm = wv >> 1, wn = wv & 1;

  // per-lane constant staging offsets
  int rA_[4], cA8_[4];
  unsigned short* dA[4];
#pragma unroll
  for (int i = 0; i < 4; ++i) {
    int g = (wv << 2) + i;
    int p = (g << 6) + lane;
    rA_[i] = p >> 3; cA8_[i] = ((p & 7) ^ (rA_[i] & 7)) << 3;
    dA[i] = &Al[0][(size_t)g << 9];
  }
  int nB_[2], cB8_[2];
  unsigned short* dG[2]; unsigned short* dU[2];
#pragma unroll
  for (int i = 0; i < 2; ++i) {
    int g = (wv << 1) + i;
    int p = (g << 6) + lane;
    nB_[i] = p >> 3; cB8_[i] = ((p & 7) ^ (nB_[i] & 7)) << 3;
    dG[i] = &Bgl[0][(size_t)g << 9];
    dU[i] = &Bul[0][(size_t)g << 9];
  }

  // current tile params + stage pointers (point at next chunk to ISSUE)
  int mt = flat % ntm, nb = flat / ntm;
  int e = 0;
  while (mt >= tpfx[e + 1]) ++e;
  size_t row0 = (size_t)mt << 8;
  int n0 = nb << 7;
  const unsigned short* sA[4]; const unsigned short* sG[2]; const unsigned short* sU[2];
#pragma unroll
  for (int i = 0; i < 4; ++i) sA[i] = Xg + (row0 + rA_[i]) * DD + cA8_[i];
  {
    const unsigned short* wgE = wgT + (size_t)e * DD * HH;
    const unsigned short* wuE = wuT + (size_t)e * DD * HH;
#pragma unroll
    for (int i = 0; i < 2; ++i) {
      int ng = n0 + nB_[i]; if (ng >= HH) ng = HH - 1;
      sG[i] = wgE + (size_t)ng * DD + cB8_[i];
      sU[i] = wuE + (size_t)ng * DD + cB8_[i];
    }
  }

  f32x4 zf = {0.f, 0.f, 0.f, 0.f};
  f32x4 ag[4][4], au[4][4];
#pragma unroll
  for (int i = 0; i < 4; ++i)
#pragma unroll
    for (int j = 0; j < 4; ++j) { ag[i][j] = zf; au[i][j] = zf; }

  // prologue: stage K-tile 0 (S0:A01, S1:A23, S2:Bg, S3:Bu)
  gload_lds16(sA[0], dA[0]); sA[0] += 64;
  gload_lds16(sA[1], dA[1]); sA[1] += 64;
  gload_lds16(sA[2], dA[2]); sA[2] += 64;
  gload_lds16(sA[3], dA[3]); sA[3] += 64;
  gload_lds16(sG[0], dG[0]); sG[0] += 64;
  gload_lds16(sG[1], dG[1]); sG[1] += 64;
  gload_lds16(sU[0], dU[0]); sU[0] += 64;
  gload_lds16(sU[1], dU[1]); sU[1] += 64;
  VMCNT2;            // S0-S2 done (Bu may lag until P0's wait)
  SCHED0; SBAR;

  size_t rowNxt = 0; int n0Nxt = 0;
  for (;;) {   // tiles
    bool hasNext = (flat + NBLK < ntiles);
    for (int kt = 0; kt < 16; ++kt) {
      bool lastG = (!hasNext) && (kt == 15);
      if (kt == 15 && hasNext) {
        // rebase stage pointers to next tile (kt'=0)
        int fN = flat + NBLK;
        int mtN = fN % ntm, nbN = fN / ntm;
        int eN = 0;
        while (mtN >= tpfx[eN + 1]) ++eN;
        rowNxt = (size_t)mtN << 8; n0Nxt = nbN << 7;
#pragma unroll
        for (int i = 0; i < 4; ++i) sA[i] = Xg + (rowNxt + rA_[i]) * DD + cA8_[i];
        const unsigned short* wgE = wgT + (size_t)eN * DD * HH;
        const unsigned short* wuE = wuT + (size_t)eN * DD * HH;
#pragma unroll
        for (int i = 0; i < 2; ++i) {
          int ng = n0Nxt + nB_[i]; if (ng >= HH) ng = HH - 1;
          sG[i] = wgE + (size_t)ng * DD + cB8_[i];
          sU[i] = wuE + (size_t)ng * DD + cB8_[i];
        }
      }
      int cur = kt & 1, wb = cur ^ 1;
      const unsigned short* alb  = &Al[0][0]  + ((size_t)cur << 14);
      const unsigned short* bglb = &Bgl[0][0] + ((size_t)cur << 13);
      const unsigned short* bulb = &Bul[0][0] + ((size_t)cur << 13);
      s16x8 af[4], bg[4], bu[4];
      // ===== P0: ks0 gate =====
#pragma unroll
      for (int fm = 0; fm < 4; ++fm) {
        int r = (wm << 6) + (fm << 4) + (lane & 15);
        af[fm] = *(const s16x8*)(alb + (r << 6) + (((lane >> 4) ^ (r & 7)) << 3));
      }
#pragma unroll
      for (int fn = 0; fn < 4; ++fn) {
        int n = (wn << 6) + (fn << 4) + (lane & 15);
        bg[fn] = *(const s16x8*)(bglb + (n << 6) + (((lane >> 4) ^ (n & 7)) << 3));
      }
      if (!lastG) {
        gload_lds16(sA[0], dA[0] + ((size_t)wb << 14)); sA[0] += 64;
        gload_lds16(sA[1], dA[1] + ((size_t)wb << 14)); sA[1] += 64;
        VMCNT2;   // retire S3(kt): Bu becomes readable after barrier
      } else {
        VMCNT0;
      }
      SCHED0; SBAR;
      LGKM0; SCHED0;
      __builtin_amdgcn_s_setprio(1);
#pragma unroll
      for (int fm = 0; fm < 4; ++fm)
#pragma unroll
        for (int fn = 0; fn < 4; ++fn)
          ag[fm][fn] = __builtin_amdgcn_mfma_f32_16x16x32_bf16(af[fm], bg[fn], ag[fm][fn], 0, 0, 0);
      __builtin_amdgcn_s_setprio(0);
      SBAR;
      // ===== P1: ks0 up =====
#pragma unroll
      for (int fn = 0; fn < 4; ++fn) {
        int n = (wn << 6) + (fn << 4) + (lane & 15);
        bu[fn] = *(const s16x8*)(bulb + (n << 6) + (((lane >> 4) ^ (n & 7)) << 3));
      }
      if (!lastG) {
        gload_lds16(sA[2], dA[2] + ((size_t)wb << 14)); sA[2] += 64;
        gload_lds16(sA[3], dA[3] + ((size_t)wb << 14)); sA[3] += 64;
      }
      SCHED0; SBAR;
      LGKM0; SCHED0;
      __builtin_amdgcn_s_setprio(1);
#pragma unroll
      for (int fm = 0; fm < 4; ++fm)
#pragma unroll
        for (int fn = 0; fn < 4; ++fn)
          au[fm][fn] = __builtin_amdgcn_mfma_f32_16x16x32_bf16(af[fm], bu[fn], au[fm][fn], 0, 0, 0);
      __builtin_amdgcn_s_setprio(0);
      SBAR;
      // ===== P2: ks1 gate =====
#pragma unroll
      for (int fm = 0; fm < 4; ++fm) {
        int r = (wm << 6) + (fm << 4) + (lane & 15);
        af[fm] = *(const s16x8*)(alb + (r << 6) + (((4 + (lane >> 4)) ^ (r & 7)) << 3));
      }
#pragma unroll
      for (int fn = 0; fn < 4; ++fn) {
        int n = (wn << 6) + (fn << 4) + (lane & 15);
        bg[fn] = *(const s16x8*)(bglb + (n << 6) + (((4 + (lane >> 4)) ^ (n & 7)) << 3));
      }
      if (!lastG) {
        gload_lds16(sG[0], dG[0] + ((size_t)wb << 13)); sG[0] += 64;
        gload_lds16(sG[1], dG[1] + ((size_t)wb << 13)); sG[1] += 64;
      }
      SCHED0; SBAR;
      LGKM0; SCHED0;
      __builtin_amdgcn_s_setprio(1);
#pragma unroll
      for (int fm = 0; fm < 4; ++fm)
#pragma unroll
        for (int fn = 0; fn < 4; ++fn)
          ag[fm][fn] = __builtin_amdgcn_mfma_f32_16x16x32_bf16(af[fm], bg[fn], ag[fm][fn], 0, 0, 0);
      __builtin_amdgcn_s_setprio(0);
      SBAR;
      // ===== P3: ks1 up =====
#pragma unroll
      for (int fn = 0; fn < 4; ++fn) {
        int n = (wn << 6) + (fn << 4) + (lane & 15);
        bu[fn] = *(const s16x8*)(bulb + (n << 6) + (((4 + (lane >> 4)) ^ (n & 7)) << 3));
      }
      if (!lastG) {
        gload_lds16(sU[0], dU[0] + ((size_t)wb << 13)); sU[0] += 64;
        gload_lds16(sU[1], dU[1] + ((size_t)wb << 13)); sU[1] += 64;
        VMCNT2;   // retire next K-step's S0-S2 (A+Bg)
      }
      SCHED0; SBAR;
      LGKM0; SCHED0;
      __builtin_amdgcn_s_setprio(1);
#pragma unroll
      for (int fm = 0; fm < 4; ++fm)
#pragma unroll
        for (int fn = 0; fn < 4; ++fn)
          au[fm][fn] = __builtin_amdgcn_mfma_f32_16x16x32_bf16(af[fm], bu[fn], au[fm][fn], 0, 0, 0);
      __builtin_amdgcn_s_setprio(0);
      SBAR;
    }
    // epilogue tile (row0, n0): silu(g)*u -> bf16 (overlaps next tile's loads)
#pragma unroll
    for (int fm = 0; fm < 4; ++fm)
#pragma unroll
      for (int fn = 0; fn < 4; ++fn)
#pragma unroll
        for (int j = 0; j < 4; ++j) {
          int cc = n0 + (wn << 6) + (fn << 4) + (lane & 15);
          if (cc < HH) {
            float gv = ag[fm][fn][j];
            float uv = au[fm][fn][j];
            float hv = gv / (1.f + __expf(-gv)) * uv;
            int r = (wm << 6) + (fm << 4) + ((lane >> 4) << 2) + j;
            hbuf[(row0 + r) * HH + (size_t)cc] = (unsigned short)f2bf1(hv);
          }
          ag[fm][fn][j] = 0.f; au[fm][fn][j] = 0.f;
        }
    if (!hasNext) break;
    row0 = rowNxt; n0 = n0Nxt;
    flat += NBLK;
  }
}

// ---------------- FC2: persistent blocks, continuous 2-phase pipeline ----------------
// tile 256M x 128N x 64K; 8 waves; A dbuf, B triple-buffer (staged 2 ahead)
__global__ __launch_bounds__(512, 1) void k_fc2t(
    const unsigned short* __restrict__ hbuf, const unsigned short* __restrict__ wdT,
    const int* __restrict__ cnt, const int* __restrict__ tpfx,
    const int* __restrict__ tok, const float* __restrict__ wgt,
    float* __restrict__ out) {
  __shared__ unsigned short Al[2][256 * 64];   // 64 KB
  __shared__ unsigned short Bl[3][128 * 64];   // 48 KB
  int ntm = tpfx[EE];
  int ntiles = ntm * 8;
  int flat = blockIdx.x;                       // flat = nb*ntm + mt
  if (flat >= ntiles) return;
  int tid = threadIdx.x, wv = tid >> 6, lane = tid & 63;
  int wm = wv >> 1, wn = wv & 1;

  int rA_[4], cA8_[4];
  unsigned short* dA[4];
#pragma unroll
  for (int i = 0; i < 4; ++i) {
    int g = (wv << 2) + i;
    int p = (g << 6) + lane;
    rA_[i] = p >> 3; cA8_[i] = ((p & 7) ^ (rA_[i] & 7)) << 3;
    dA[i] = &Al[0][(size_t)g << 9];
  }
  int nB_[2], cB8_[2];
  unsigned short* dB[2];
#pragma unroll
  for (int i = 0; i < 2; ++i) {
    int g = (wv << 1) + i;
    int p = (g << 6) + lane;
    nB_[i] = p >> 3; cB8_[i] = ((p & 7) ^ (nB_[i] & 7)) << 3;
    dB[i] = &Bl[0][(size_t)g << 9];
  }

  int mt = flat % ntm, nb = flat / ntm;
  int e = 0;
  while (mt >= tpfx[e + 1]) ++e;
  size_t row0 = (size_t)mt << 8;
  int n0 = nb << 7;
  int mrem = cnt[e] - ((mt - tpfx[e]) << 8);
  if (mrem > 256) mrem = 256;
  const unsigned short* sA[4]; const unsigned short* sB[2];
#pragma unroll
  for (int i = 0; i < 4; ++i) sA[i] = hbuf + (row0 + rA_[i]) * HH + cA8_[i];
  {
    const unsigned short* wdE = wdT + (size_t)e * DD * HH;
#pragma unroll
    for (int i = 0; i < 2; ++i) sB[i] = wdE + (size_t)(n0 + nB_[i]) * HH + cB8_[i];
  }

  f32x4 zf = {0.f, 0.f, 0.f, 0.f};
  f32x4 acc[4][4];
#pragma unroll
  for (int i = 0; i < 4; ++i)
#pragma unroll
    for (int j = 0; j < 4; ++j) acc[i][j] = zf;

  // prologue: B(0)->slot0, A(0)->buf0, B(1)->slot1
  gload_lds16(sB[0], dB[0]); sB[0] += 64;
  gload_lds16(sB[1], dB[1]); sB[1] += 64;
  gload_lds16(sA[0], dA[0]); sA[0] += 64;
  gload_lds16(sA[1], dA[1]); sA[1] += 64;
  gload_lds16(sA[2], dA[2]); sA[2] += 64;
  gload_lds16(sA[3], dA[3]); sA[3] += 64;
  gload_lds16(sB[0], dB[0] + 8192); sB[0] += 64;
  gload_lds16(sB[1], dB[1] + 8192); sB[1] += 64;
  VMCNT2;     // B(0)+A(0) done; B(1) in flight
  SCHED0; SBAR;

  size_t rowNxt = 0; int n0Nxt = 0, mremNxt = 0;
  const unsigned short* wdENxt = wdT;
  int curA = 0, ib = 0;                        // A parity, B consume slot
  for (;;) {
    bool hasNext = (flat + NBLK < ntiles);
    for (int kt = 0; kt < 43; ++kt) {
      bool endA = (!hasNext) && (kt == 42);    // no A issue
      bool endB = (!hasNext) && (kt >= 41);    // no B issue
      if (hasNext && kt == 41) {
        // next-tile params + B rebase (B staged 2 ahead crosses boundary first)
        int fN = flat + NBLK;
        int mtN = fN % ntm, nbN = fN / ntm;
        int eN = 0;
        while (mtN >= tpfx[eN + 1]) ++eN;
        rowNxt = (size_t)mtN << 8; n0Nxt = nbN << 7;
        mremNxt = cnt[eN] - ((mtN - tpfx[eN]) << 8);
        if (mremNxt > 256) mremNxt = 256;
        wdENxt = wdT + (size_t)eN * DD * HH;
#pragma unroll
        for (int i = 0; i < 2; ++i) sB[i] = wdENxt + (size_t)(n0Nxt + nB_[i]) * HH + cB8_[i];
      }
      if (hasNext && kt == 42) {
#pragma unroll
        for (int i = 0; i < 4; ++i) sA[i] = hbuf + (rowNxt + rA_[i]) * HH + cA8_[i];
      }
      int wbA = curA ^ 1;
      int ibw = (ib >= 1) ? ib - 1 : 2;        // (ib+2)%3
      const unsigned short* alb = &Al[0][0] + ((size_t)curA << 14);
      const unsigned short* blb = &Bl[0][0] + (size_t)ib * 8192;
      s16x8 af[4], bf[4];
      // ===== P0: ks0 =====
#pragma unroll
      for (int fm = 0; fm < 4; ++fm) {
        int r = (wm << 6) + (fm << 4) + (lane & 15);
        af[fm] = *(const s16x8*)(alb + (r << 6) + (((lane >> 4) ^ (r & 7)) << 3));
      }
#pragma unroll
      for (int fn = 0; fn < 4; ++fn) {
        int n = (wn << 6) + (fn << 4) + (lane & 15);
        bf[fn] = *(const s16x8*)(blb + (n << 6) + (((lane >> 4) ^ (n & 7)) << 3));
      }
      if (!endA) {
        gload_lds16(sA[0], dA[0] + ((size_t)wbA << 14)); sA[0] += 64;
        gload_lds16(sA[1], dA[1] + ((size_t)wbA << 14)); sA[1] += 64;
        gload_lds16(sA[2], dA[2] + ((size_t)wbA << 14)); sA[2] += 64;
        gload_lds16(sA[3], dA[3] + ((size_t)wbA << 14)); sA[3] += 64;
      }
      SCHED0; SBAR;
      LGKM0; SCHED0;
      __builtin_amdgcn_s_setprio(1);
#pragma unroll
      for (int fm = 0; fm < 4; ++fm)
#pragma unroll
        for (int fn = 0; fn < 4; ++fn)
          acc[fm][fn] = __builtin_amdgcn_mfma_f32_16x16x32_bf16(af[fm], bf[fn], acc[fm][fn], 0, 0, 0);
      __builtin_amdgcn_s_setprio(0);
      SBAR;
      // ===== P1: ks1 =====
#pragma unroll
      for (int fm = 0; fm < 4; ++fm) {
        int r = (wm << 6) + (fm << 4) + (lane & 15);
        af[fm] = *(const s16x8*)(alb + (r << 6) + (((4 + (lane >> 4)) ^ (r & 7)) << 3));
      }
#pragma unroll
      for (int fn = 0; fn < 4; ++fn) {
        int n = (wn << 6) + (fn << 4) + (lane & 15);
        bf[fn] = *(const s16x8*)(blb + (n << 6) + (((4 + (lane >> 4)) ^ (n & 7)) << 3));
      }
      if (!endB) {
        gload_lds16(sB[0], dB[0] + (size_t)ibw * 8192); sB[0] += 64;
        gload_lds16(sB[1], dB[1] + (size_t)ibw * 8192); sB[1] += 64;
      }
      if (endB) { VMCNT0; } else { VMCNT2; }   // retire next K-step's A+B
      SCHED0; SBAR;
      LGKM0; SCHED0;
      __builtin_amdgcn_s_setprio(1);
#pragma unroll
      for (int fm = 0; fm < 4; ++fm)
#pragma unroll
        for (int fn = 0; fn < 4; ++fn)
          acc[fm][fn] = __builtin_amdgcn_mfma_f32_16x16x32_bf16(af[fm], bf[fn], acc[fm][fn], 0, 0, 0);
      __builtin_amdgcn_s_setprio(0);
      SBAR;
      curA ^= 1;
      ib = (ib >= 2) ? 0 : ib + 1;
    }
    // epilogue: weighted scatter-add (overlaps next tile's loads)
#pragma unroll
    for (int fm = 0; fm < 4; ++fm)
#pragma unroll
      for (int j = 0; j < 4; ++j) {
        int r = (wm << 6) + (fm << 4) + ((lane >> 4) << 2) + j;
        if (r < mrem) {
          int tk = tok[row0 + r];
          float cw = wgt[row0 + r];
          float* ob = out + (size_t)tk * DD + (size_t)(n0 + (wn << 6) + (lane & 15));
#pragma unroll
          for (int fn = 0; fn < 4; ++fn)
            atomicAdd(ob + (fn << 4), acc[fm][fn][j] * cw);
        }
#pragma unroll
        for (int fn = 0; fn < 4; ++fn) acc[fm][fn][j] = 0.f;
      }
    if (!hasNext) break;
    row0 = rowNxt; n0 = n0Nxt; mrem = mremNxt;
    flat += NBLK;
  }
}

// ================= fallback kernels (128-row tiles over 256-aligned segments) =================
__global__ __launch_bounds__(256) void k_fc1_cv(
    const unsigned short* __restrict__ Xg, const float* __restrict__ wg,
    const float* __restrict__ wu, const int* __restrict__ tpfx,
    unsigned short* __restrict__ hbuf) {
  __shared__ unsigned short Al[128 * 64];
  __shared__ unsigned short Bgl[64 * 64];
  __shared__ unsigned short Bul[64 * 64];
  int mt = blockIdx.x;
  if (mt >= 2 * tpfx[EE]) return;
  int e = 0;
  while (mt >= 2 * tpfx[e + 1]) ++e;
  int n0 = blockIdx.y << 6;
  size_t row0 = (size_t)mt << 7;
  const float* wge = wg + (size_t)e * DD * HH;
  const float* wue = wu + (size_t)e * DD * HH;
  int tid = threadIdx.x, wv = tid >> 6, lane = tid & 63;
  int wm = wv >> 1, wn = wv & 1;
  f32x4 zf = {0.f, 0.f, 0.f, 0.f};
  f32x4 ag[4][2], au[4][2];
#pragma unroll
  for (int i = 0; i < 4; ++i)
#pragma unroll
    for (int j = 0; j < 2; ++j) { ag[i][j] = zf; au[i][j] = zf; }
  for (int kt = 0; kt < DD / 64; ++kt) {
    int k0 = kt << 6;
#pragma unroll
    for (int i = 0; i < 4; ++i) {
      int g = (wv << 2) + i;
      int p = (g << 6) + lane;
      int r = p >> 3, c = (p & 7) ^ (r & 7);
      gload_lds16(Xg + (row0 + r) * DD + (size_t)(k0 + (c << 3)), Al + ((size_t)g << 9));
    }
#pragma unroll
    for (int a2 = 0; a2 < 2; ++a2) {
      int idx = tid + (a2 << 8);
      int kk = (idx >> 4) << 1;
      int nn = (idx & 15) << 2;
      const float* pg = wge + (size_t)(k0 + kk) * HH + (n0 + nn);
      const float* pu = wue + (size_t)(k0 + kk) * HH + (n0 + nn);
      float4 g0 = *(const float4*)pg;
      float4 g1 = *(const float4*)(pg + HH);
      float4 u0 = *(const float4*)pu;
      float4 u1 = *(const float4*)(pu + HH);
      const float* g0f = (const float*)&g0; const float* g1f = (const float*)&g1;
      const float* u0f = (const float*)&u0; const float* u1f = (const float*)&u1;
      int kb = kk << 1, ch = kb >> 4, inb = kb & 15;
#pragma unroll
      for (int j = 0; j < 4; ++j) {
        int n = nn + j;
        int off = (n << 7) + ((ch ^ bswz(n)) << 4) + inb;
        *(unsigned int*)((char*)Bgl + off) = f2bf2(g0f[j], g1f[j]);
        *(unsigned int*)((char*)Bul + off) = f2bf2(u0f[j], u1f[j]);
      }
    }
    __syncthreads();
#pragma unroll
    for (int ks = 0; ks < 2; ++ks) {
      int cch = (ks << 2) + (lane >> 4);
      s16x8 af[4];
#pragma unroll
      for (int fm = 0; fm < 4; ++fm) {
        int r = (wm << 6) + (fm << 4) + (lane & 15);
        af[fm] = *(const s16x8*)(Al + (r << 6) + ((cch ^ (r & 7)) << 3));
      }
      s16x8 bg[2], bu[2];
#pragma unroll
      for (int fn = 0; fn < 2; ++fn) {
        int n = (wn << 5) + (fn << 4) + (lane & 15);
        int o = (n << 6) + ((cch ^ bswz(n)) << 3);
        bg[fn] = *(const s16x8*)(Bgl + o);
        bu[fn] = *(const s16x8*)(Bul + o);
      }
#pragma unroll
      for (int fm = 0; fm < 4; ++fm)
#pragma unroll
        for (int fn = 0; fn < 2; ++fn) {
          ag[fm][fn] = __builtin_amdgcn_mfma_f32_16x16x32_bf16(af[fm], bg[fn], ag[fm][fn], 0, 0, 0);
          au[fm][fn] = __builtin_amdgcn_mfma_f32_16x16x32_bf16(af[fm], bu[fn], au[fm][fn], 0, 0, 0);
        }
    }
    __syncthreads();
  }
#pragma unroll
  for (int fm = 0; fm < 4; ++fm)
#pragma unroll
    for (int fn = 0; fn < 2; ++fn)
#pragma unroll
      for (int j = 0; j < 4; ++j) {
        float gv = ag[fm][fn][j];
        float uv = au[fm][fn][j];
        float hv = gv / (1.f + __expf(-gv)) * uv;
        int r = (wm << 6) + (fm << 4) + ((lane >> 4) << 2) + j;
        int cc = (wn << 5) + (fn << 4) + (lane & 15);
        hbuf[(row0 + r) * HH + (size_t)(n0 + cc)] = (unsigned short)f2bf1(hv);
      }
}

__global__ __launch_bounds__(256) void k_fc2_cv(
    const unsigned short* __restrict__ hbuf, const float* __restrict__ wd,
    const int* __restrict__ cnt, const int* __restrict__ tpfx,
    const int* __restrict__ tok, const float* __restrict__ wgt,
    float* __restrict__ out) {
  __shared__ unsigned short Al[128 * 64];
  __shared__ unsigned short Bl[128 * 64];
  int mt = blockIdx.x;
  if (mt >= 2 * tpfx[EE]) return;
  int e = 0;
  while (mt >= 2 * tpfx[e + 1]) ++e;
  int n0 = blockIdx.y << 7;
  size_t row0 = (size_t)mt << 7;
  int mrem = cnt[e] - ((mt - 2 * tpfx[e]) << 7);
  if (mrem > 128) mrem = 128;
  const float* wde = wd + (size_t)e * HH * DD;
  int tid = threadIdx.x, wv = tid >> 6, lane = tid & 63;
  int wm = wv >> 1, wn = wv & 1;
  f32x4 zf = {0.f, 0.f, 0.f, 0.f};
  f32x4 acc[4][4];
#pragma unroll
  for (int i = 0; i < 4; ++i)
#pragma unroll
    for (int j = 0; j < 4; ++j) acc[i][j] = zf;
  for (int kt = 0; kt < HH / 64; ++kt) {
    int k0 = kt << 6;
#pragma unroll
    for (int i = 0; i < 4; ++i) {
      int g = (wv << 2) + i;
      int p = (g << 6) + lane;
      int r = p >> 3, c = (p & 7) ^ (r & 7);
      gload_lds16(hbuf + (row0 + r) * HH + (size_t)(k0 + (c << 3)), Al + ((size_t)g << 9));
    }
#pragma unroll
    for (int a2 = 0; a2 < 4; ++a2) {
      int idx = tid + (a2 << 8);
      int kk = (idx >> 5) << 1;
      int nn = (idx & 31) << 2;
      const float* pb = wde + (size_t)(k0 + kk) * DD + (n0 + nn);
      float4 b0 = *(const float4*)pb;
      float4 b1 = *(const float4*)(pb + DD);
      const float* b0f = (const float*)&b0;
      const float* b1f = (const float*)&b1;
      int kb = kk << 1, ch = kb >> 4, inb = kb & 15;
#pragma unroll
      for (int j = 0; j < 4; ++j) {
        int n = nn + j;
        int off = (n << 7) + ((ch ^ bswz(n)) << 4) + inb;
        *(unsigned int*)((char*)Bl + off) = f2bf2(b0f[j], b1f[j]);
      }
    }
    __syncthreads();
#pragma unroll
    for (int ks = 0; ks < 2; ++ks) {
      int cch = (ks << 2) + (lane >> 4);
      s16x8 af[4], bf[4];
#pragma unroll
      for (int fm = 0; fm < 4; ++fm) {
        int r = (wm << 6) + (fm << 4) + (lane & 15);
        af[fm] = *(const s16x8*)(Al + (r << 6) + ((cch ^ (r & 7)) << 3));
      }
#pragma unroll
      for (int fn = 0; fn < 4; ++fn) {
        int n = (wn << 6) + (fn << 4) + (lane & 15);
        bf[fn] = *(const s16x8*)(Bl + (n << 6) + ((cch ^ bswz(n)) << 3));
      }
#pragma unroll
      for (int fm = 0; fm < 4; ++fm)
#pragma unroll
        for (int fn = 0; fn < 4; ++fn)
          acc[fm][fn] = __builtin_amdgcn_mfma_f32_16x16x32_bf16(af[fm], bf[fn], acc[fm][fn], 0, 0, 0);
    }
    __syncthreads();
  }
#pragma unroll
  for (int fm = 0; fm < 4; ++fm)
#pragma unroll
    for (int j = 0; j < 4; ++j) {
      int r = (wm << 6) + (fm << 4) + ((lane >> 4) << 2) + j;
      if (r < mrem) {
        int tk = tok[row0 + r];
        float cw = wgt[row0 + r];
        float* ob = out + (size_t)tk * DD + (size_t)(n0 + (wn << 6) + (lane & 15));
#pragma unroll
        for (int fn = 0; fn < 4; ++fn)
          atomicAdd(ob + (fn << 4), acc[fm][fn][j] * cw);
      }
    }
}

extern "C" void kernel_launch(void* const* d_in, const int* in_sizes, int n_in,
                              void* d_out, int out_size, void* d_ws, size_t ws_size,
                              hipStream_t stream) {
  const float* x  = (const float*)d_in[0];
  const float* rw = (const float*)d_in[1];
  const float* wg = (const float*)d_in[2];
  const float* wu = (const float*)d_in[3];
  const float* wd = (const float*)d_in[4];
  float* out = (float*)d_out;

  // workspace layout (256-row padded segments; max 18432 gathered rows)
  char* w = (char*)d_ws;
  int* cnt    = (int*)(w + 0);
  int* cursor = (int*)(w + 32);
  int* tpfx   = (int*)(w + 64);
  int* topi   = (int*)(w + 256);                      // 16384 ints
  float* topw = (float*)(w + 65792);                  // 16384 f32
  int* tok    = (int*)(w + 131328);                   // 18432 ints
  float* wgt  = (float*)(w + 205056);                 // 18432 f32
  unsigned short* Xg  = (unsigned short*)(w + 278784);        // 37,748,736 B
  unsigned short* hb  = (unsigned short*)(w + 38027520ULL);   // 101,449,728 B
  unsigned short* wgT = (unsigned short*)(w + 139477248ULL);  // 45,088,768 B
  unsigned short* wuT = (unsigned short*)(w + 184566016ULL);  // 45,088,768 B
  unsigned short* wdT2 = (unsigned short*)(w + 229654784ULL); // 45,088,768 B (big path)
  const size_t NEED  = 229654784ULL;                  // mid path (wdT reuses wgT)
  const size_t NEED2 = 274743552ULL;                  // big path (separate wdT)

  bool mid = ws_size >= NEED;
  bool big = ws_size >= NEED2;

  // fused prep: router + out-zero + cursor init (+ weight transposes if ws allows)
  int prep_grid = NRB + ZB + (big ? 3 * NTB : (mid ? 2 * NTB : 0));
  k_prep<<<prep_grid, 256, 0, stream>>>(x, rw, topi, topw, cursor, out,
                                        wg, wgT, wu, wuT, wd, wdT2);
  k_assign<<<T_TOKENS / 256, 256, 0, stream>>>(topi, cursor);
  k_offsets<<<1, 64, 0, stream>>>(cursor, cnt, tpfx);
  k_copy_pad<<<2560, 256, 0, stream>>>(x, topi, topw, tpfx, cnt, tok, wgt, Xg);

  if (mid) {
    k_fc1t<<<NBLK, 512, 0, stream>>>(Xg, wgT, wuT, tpfx, hb);
    unsigned short* wdTp = wdT2;
    if (!big) {
      k_wtrans<<<NTB, 256, 0, stream>>>(wd, wgT, HH, DD);  // over wgT slot
      wdTp = wgT;
    }
    k_fc2t<<<NBLK, 512, 0, stream>>>(hb, wdTp, cnt, tpfx, tok, wgt, out);
  } else {
    k_fc1_cv<<<dim3(MT1, HH / 64), 256, 0, stream>>>(Xg, wg, wu, tpfx, hb);
    k_fc2_cv<<<dim3(MT1, DD / 128), 256, 0, stream>>>(hb, wd, cnt, tpfx, tok, wgt, out);
  }
}

// Round 9
// 516.275 us; speedup vs baseline: 1.4024x; 1.0997x over previous
//
#include <hip/hip_runtime.h>
#include <hip/hip_bf16.h>
#include <math.h>

// Problem constants
#define T_TOKENS 8192      // B*S
#define DD 1024            // embed dim
#define HH 2752            // swiglu hidden (43*64)
#define EE 8               // experts
#define NBLK 256           // persistent blocks for fc1 (1 per CU)
#define NBLK2 512          // fc2 blocks (2 per CU)
#define MT1 144            // 128-row tiles (fallback kernels)
#define NRB 2048           // router blocks in k_prep
#define NTB 5504           // transpose tiles per weight tensor (8*16*43)

typedef __attribute__((ext_vector_type(8))) short s16x8;
typedef __attribute__((ext_vector_type(4))) float f32x4;

#define VMCNT0 asm volatile("s_waitcnt vmcnt(0)" ::: "memory")
#define VMCNT2 asm volatile("s_waitcnt vmcnt(2)" ::: "memory")
#define VMCNT4 asm volatile("s_waitcnt vmcnt(4)" ::: "memory")
#define LGKM0  asm volatile("s_waitcnt lgkmcnt(0)" ::: "memory")
#define SBAR   __builtin_amdgcn_s_barrier()
#define SCHED0 __builtin_amdgcn_sched_barrier(0)

__device__ __forceinline__ unsigned int f2bf1(float f) {
  unsigned int u = __float_as_uint(f);
  return (u + 0x7FFFu + ((u >> 16) & 1u)) >> 16;   // RNE fp32->bf16
}
__device__ __forceinline__ unsigned int f2bf2(float lo, float hi) {
  return f2bf1(lo) | (f2bf1(hi) << 16);
}
__device__ __forceinline__ float bf2f(unsigned short u) {
  unsigned int x = ((unsigned int)u) << 16;
  return __uint_as_float(x);
}

__device__ __forceinline__ void gload_lds16(const void* g, void* l) {
  __builtin_amdgcn_global_load_lds((const __attribute__((address_space(1))) void*)g,
                                   (__attribute__((address_space(3))) void*)l, 16, 0, 0);
}

// legacy B-tile swizzle (fallback kernels only)
__device__ __forceinline__ int bswz(int n) {
  return ((n >> 2) & 7) ^ ((n & 3) << 1);
}

// ---- transpose+convert one 64x64 tile: fp32 [R][C] -> bf16 [C][R] ----
__device__ __forceinline__ void trans_tile(const float* __restrict__ src,
                                           unsigned short* __restrict__ dst,
                                           int R, int C, int gt, unsigned int* Lt) {
  int ctn = C >> 6;
  int tiles = (R >> 6) * ctn;
  int e = gt / tiles, t = gt % tiles;
  int rt0 = (t / ctn) << 6, ct0 = (t % ctn) << 6;
  const float* s = src + (size_t)e * R * C;
  unsigned short* d = dst + (size_t)e * R * C;
  int tid = threadIdx.x;
  int rp = tid >> 3, cg = tid & 7;
  const float* p0 = s + (size_t)(rt0 + (rp << 1)) * C + ct0 + (cg << 3);
  float4 a0 = *(const float4*)p0;
  float4 a1 = *(const float4*)(p0 + 4);
  float4 b0 = *(const float4*)(p0 + C);
  float4 b1 = *(const float4*)(p0 + C + 4);
  float va[8] = {a0.x, a0.y, a0.z, a0.w, a1.x, a1.y, a1.z, a1.w};
  float vb[8] = {b0.x, b0.y, b0.z, b0.w, b1.x, b1.y, b1.z, b1.w};
#pragma unroll
  for (int j = 0; j < 8; ++j)
    Lt[((cg << 3) + j) * 33 + rp] = f2bf2(va[j], vb[j]);
  __syncthreads();
  int c = tid >> 2, q = tid & 3;
  unsigned int o[8];
#pragma unroll
  for (int i = 0; i < 8; ++i) o[i] = Lt[c * 33 + (q << 3) + i];
  unsigned short* pd = d + (size_t)(ct0 + c) * R + rt0 + (q << 4);
  *(uint4*)pd       = make_uint4(o[0], o[1], o[2], o[3]);
  *(uint4*)(pd + 8) = make_uint4(o[4], o[5], o[6], o[7]);
}

// ---------------- fused prep: router + weight transposes + cursor init ----------------
__global__ __launch_bounds__(256) void k_prep(
    const float* __restrict__ x, const float* __restrict__ rw,
    int* __restrict__ topi, float* __restrict__ topw, int* __restrict__ cursor,
    const float* __restrict__ wg, unsigned short* __restrict__ wgT,
    const float* __restrict__ wu, unsigned short* __restrict__ wuT,
    const float* __restrict__ wd, unsigned short* __restrict__ wdT) {
  __shared__ unsigned int Lt[64 * 33];
  int bid = blockIdx.x;
  if (bid == 0 && threadIdx.x < EE) cursor[threadIdx.x] = 0;
  if (bid < NRB) {
    int t = (bid * 256 + threadIdx.x) >> 6;
    int lane = threadIdx.x & 63;
    const float* xr = x + (size_t)t * DD;
    double acc[EE];
#pragma unroll
    for (int e = 0; e < EE; ++e) acc[e] = 0.0;
#pragma unroll
    for (int i = 0; i < DD / 64; ++i) {
      int d = lane + (i << 6);
      double xv = (double)xr[d];
      const float4* rp = (const float4*)(rw + (size_t)d * EE);
      float4 r0 = rp[0], r1 = rp[1];
      acc[0] += xv * (double)r0.x; acc[1] += xv * (double)r0.y;
      acc[2] += xv * (double)r0.z; acc[3] += xv * (double)r0.w;
      acc[4] += xv * (double)r1.x; acc[5] += xv * (double)r1.y;
      acc[6] += xv * (double)r1.z; acc[7] += xv * (double)r1.w;
    }
#pragma unroll
    for (int e = 0; e < EE; ++e) {
      double v = acc[e];
#pragma unroll
      for (int off = 32; off > 0; off >>= 1) v += __shfl_down(v, off, 64);
      acc[e] = v;
    }
    if (lane == 0) {
      int i1 = 0; double l1 = acc[0];
#pragma unroll
      for (int e = 1; e < EE; ++e) if (acc[e] > l1) { l1 = acc[e]; i1 = e; }
      int i2 = -1; double l2 = -1e300;
#pragma unroll
      for (int e = 0; e < EE; ++e) if (e != i1 && acc[e] > l2) { l2 = acc[e]; i2 = e; }
      double ee = exp(l2 - l1);
      float w1 = (float)(1.0 / (1.0 + ee));
      topi[2 * t] = i1; topi[2 * t + 1] = i2;
      topw[2 * t] = w1; topw[2 * t + 1] = 1.0f - w1;
    }
  } else if (bid < NRB + NTB) {
    trans_tile(wg, wgT, DD, HH, bid - NRB, Lt);
  } else if (bid < NRB + 2 * NTB) {
    trans_tile(wu, wuT, DD, HH, bid - NRB - NTB, Lt);
  } else {
    trans_tile(wd, wdT, HH, DD, bid - NRB - 2 * NTB, Lt);
  }
}

__global__ __launch_bounds__(256) void k_assign(int* __restrict__ topi,
                                                int* __restrict__ cursor) {
  __shared__ int hist[EE];
  __shared__ int base[EE];
  int t = blockIdx.x * 256 + threadIdx.x;
  if (threadIdx.x < EE) hist[threadIdx.x] = 0;
  __syncthreads();
  int e0 = topi[2 * t], e1 = topi[2 * t + 1];
  int r0 = atomicAdd(&hist[e0], 1);
  int r1 = atomicAdd(&hist[e1], 1);
  __syncthreads();
  if (threadIdx.x < EE) base[threadIdx.x] = atomicAdd(&cursor[threadIdx.x], hist[threadIdx.x]);
  __syncthreads();
  topi[2 * t]     = e0 | ((base[e0] + r0) << 3);
  topi[2 * t + 1] = e1 | ((base[e1] + r1) << 3);
}

// tpfx in 256-row tile units
__global__ void k_offsets(const int* __restrict__ cursor, int* __restrict__ cnt,
                          int* __restrict__ tpfx) {
  if (threadIdx.x == 0) {
    int acc = 0;
#pragma unroll
    for (int e = 0; e < EE; ++e) {
      cnt[e] = cursor[e];
      tpfx[e] = acc;
      acc += (cursor[e] + 255) >> 8;
    }
    tpfx[EE] = acc;
  }
}

// fused copy (blocks 0..2047) + padzero (blocks 2048..2559)
__global__ void k_copy_pad(const float* __restrict__ x, const int* __restrict__ topi,
                           const float* __restrict__ topw, const int* __restrict__ tpfx,
                           const int* __restrict__ cnt,
                           int* __restrict__ tok, float* __restrict__ wgt,
                           unsigned short* __restrict__ Xg) {
  int bid = blockIdx.x;
  int lane = threadIdx.x & 63;
  if (bid < 2048) {
    int t = (bid * 256 + threadIdx.x) >> 6;
    int v0 = topi[2 * t], v1 = topi[2 * t + 1];
    int e0 = v0 & 7, e1 = v1 & 7;
    int r0 = (tpfx[e0] << 8) + (v0 >> 3);
    int r1 = (tpfx[e1] << 8) + (v1 >> 3);
    if (lane == 0) {
      tok[r0] = t; wgt[r0] = topw[2 * t];
      tok[r1] = t; wgt[r1] = topw[2 * t + 1];
    }
    const float4* xp = (const float4*)(x + (size_t)t * DD) + (lane << 2);
    float4 a = xp[0], b = xp[1], c = xp[2], d = xp[3];
    uint4 o0, o1;
    o0.x = f2bf2(a.x, a.y); o0.y = f2bf2(a.z, a.w);
    o0.z = f2bf2(b.x, b.y); o0.w = f2bf2(b.z, b.w);
    o1.x = f2bf2(c.x, c.y); o1.y = f2bf2(c.z, c.w);
    o1.z = f2bf2(d.x, d.y); o1.w = f2bf2(d.z, d.w);
    uint4* p0 = (uint4*)(Xg + (size_t)r0 * DD) + (lane << 1);
    p0[0] = o0; p0[1] = o1;
    uint4* p1 = (uint4*)(Xg + (size_t)r1 * DD) + (lane << 1);
    p1[0] = o0; p1[1] = o1;
  } else {
    int wid = ((bid - 2048) * 256 + threadIdx.x) >> 6;
    int e = wid >> 8, i = wid & 255;
    int c = cnt[e];
    int padded = ((c + 255) >> 8) << 8;
    if (c + i < padded) {
      size_t row = ((size_t)tpfx[e] << 8) + (size_t)(c + i);
      uint4 z = make_uint4(0u, 0u, 0u, 0u);
      uint4* p = (uint4*)(Xg + row * DD) + (lane << 1);
      p[0] = z; p[1] = z;
    }
  }
}

// standalone transpose (mid-ws path: wd -> wgT slot between fc1 and fc2)
__global__ __launch_bounds__(256) void k_wtrans(const float* __restrict__ src,
                                                unsigned short* __restrict__ dst,
                                                int R, int C) {
  __shared__ unsigned int Lt[64 * 33];
  trans_tile(src, dst, R, C, blockIdx.x, Lt);
}

// ---------------- FC1: persistent blocks, continuous 4-phase pipeline (unchanged r7/r8) ----------------
__global__ __launch_bounds__(512, 1) void k_fc1t(
    const unsigned short* __restrict__ Xg, const unsigned short* __restrict__ wgT,
    const unsigned short* __restrict__ wuT, const int* __restrict__ tpfx,
    unsigned short* __restrict__ hbuf) {
  __shared__ unsigned short Al[2][256 * 64];   // 64 KB
  __shared__ unsigned short Bgl[2][128 * 64];  // 32 KB
  __shared__ unsigned short Bul[2][128 * 64];  // 32 KB
  int ntm = tpfx[EE];
  int ntiles = ntm * 22;
  int flat = blockIdx.x;
  if (flat >= ntiles) return;
  int tid = threadIdx.x, wv = tid >> 6, lane = tid & 63;
  int wm = wv >> 1, wn = wv & 1;

  int rA_[4], cA8_[4];
  unsigned short* dA[4];
#pragma unroll
  for (int i = 0; i < 4; ++i) {
    int g = (wv << 2) + i;
    int p = (g << 6) + lane;
    rA_[i] = p >> 3; cA8_[i] = ((p & 7) ^ (rA_[i] & 7)) << 3;
    dA[i] = &Al[0][(size_t)g << 9];
  }
  int nB_[2], cB8_[2];
  unsigned short* dG[2]; unsigned short* dU[2];
#pragma unroll
  for (int i = 0; i < 2; ++i) {
    int g = (wv << 1) + i;
    int p = (g << 6) + lane;
    nB_[i] = p >> 3; cB8_[i] = ((p & 7) ^ (nB_[i] & 7)) << 3;
    dG[i] = &Bgl[0][(size_t)g << 9];
    dU[i] = &Bul[0][(size_t)g << 9];
  }

  int mt = flat % ntm, nb = flat / ntm;
  int e = 0;
  while (mt >= tpfx[e + 1]) ++e;
  size_t row0 = (size_t)mt << 8;
  int n0 = nb << 7;
  const unsigned short* sA[4]; const unsigned short* sG[2]; const unsigned short* sU[2];
#pragma unroll
  for (int i = 0; i < 4; ++i) sA[i] = Xg + (row0 + rA_[i]) * DD + cA8_[i];
  {
    const unsigned short* wgE = wgT + (size_t)e * DD * HH;
    const unsigned short* wuE = wuT + (size_t)e * DD * HH;
#pragma unroll
    for (int i = 0; i < 2; ++i) {
      int ng = n0 + nB_[i]; if (ng >= HH) ng = HH - 1;
      sG[i] = wgE + (size_t)ng * DD + cB8_[i];
      sU[i] = wuE + (size_t)ng * DD + cB8_[i];
    }
  }

  f32x4 zf = {0.f, 0.f, 0.f, 0.f};
  f32x4 ag[4][4], au[4][4];
#pragma unroll
  for (int i = 0; i < 4; ++i)
#pragma unroll
    for (int j = 0; j < 4; ++j) { ag[i][j] = zf; au[i][j] = zf; }

  gload_lds16(sA[0], dA[0]); sA[0] += 64;
  gload_lds16(sA[1], dA[1]); sA[1] += 64;
  gload_lds16(sA[2], dA[2]); sA[2] += 64;
  gload_lds16(sA[3], dA[3]); sA[3] += 64;
  gload_lds16(sG[0], dG[0]); sG[0] += 64;
  gload_lds16(sG[1], dG[1]); sG[1] += 64;
  gload_lds16(sU[0], dU[0]); sU[0] += 64;
  gload_lds16(sU[1], dU[1]); sU[1] += 64;
  VMCNT2;
  SCHED0; SBAR;

  size_t rowNxt = 0; int n0Nxt = 0;
  for (;;) {
    bool hasNext = (flat + NBLK < ntiles);
    for (int kt = 0; kt < 16; ++kt) {
      bool lastG = (!hasNext) && (kt == 15);
      if (kt == 15 && hasNext) {
        int fN = flat + NBLK;
        int mtN = fN % ntm, nbN = fN / ntm;
        int eN = 0;
        while (mtN >= tpfx[eN + 1]) ++eN;
        rowNxt = (size_t)mtN << 8; n0Nxt = nbN << 7;
#pragma unroll
        for (int i = 0; i < 4; ++i) sA[i] = Xg + (rowNxt + rA_[i]) * DD + cA8_[i];
        const unsigned short* wgE = wgT + (size_t)eN * DD * HH;
        const unsigned short* wuE = wuT + (size_t)eN * DD * HH;
#pragma unroll
        for (int i = 0; i < 2; ++i) {
          int ng = n0Nxt + nB_[i]; if (ng >= HH) ng = HH - 1;
          sG[i] = wgE + (size_t)ng * DD + cB8_[i];
          sU[i] = wuE + (size_t)ng * DD + cB8_[i];
        }
      }
      int cur = kt & 1, wb = cur ^ 1;
      const unsigned short* alb  = &Al[0][0]  + ((size_t)cur << 14);
      const unsigned short* bglb = &Bgl[0][0] + ((size_t)cur << 13);
      const unsigned short* bulb = &Bul[0][0] + ((size_t)cur << 13);
      s16x8 af[4], bg[4], bu[4];
      // P0: ks0 gate
#pragma unroll
      for (int fm = 0; fm < 4; ++fm) {
        int r = (wm << 6) + (fm << 4) + (lane & 15);
        af[fm] = *(const s16x8*)(alb + (r << 6) + (((lane >> 4) ^ (r & 7)) << 3));
      }
#pragma unroll
      for (int fn = 0; fn < 4; ++fn) {
        int n = (wn << 6) + (fn << 4) + (lane & 15);
        bg[fn] = *(const s16x8*)(bglb + (n << 6) + (((lane >> 4) ^ (n & 7)) << 3));
      }
      if (!lastG) {
        gload_lds16(sA[0], dA[0] + ((size_t)wb << 14)); sA[0] += 64;
        gload_lds16(sA[1], dA[1] + ((size_t)wb << 14)); sA[1] += 64;
        VMCNT2;
      } else {
        VMCNT0;
      }
      SCHED0; SBAR;
      LGKM0; SCHED0;
      __builtin_amdgcn_s_setprio(1);
#pragma unroll
      for (int fm = 0; fm < 4; ++fm)
#pragma unroll
        for (int fn = 0; fn < 4; ++fn)
          ag[fm][fn] = __builtin_amdgcn_mfma_f32_16x16x32_bf16(af[fm], bg[fn], ag[fm][fn], 0, 0, 0);
      __builtin_amdgcn_s_setprio(0);
      SBAR;
      // P1: ks0 up
#pragma unroll
      for (int fn = 0; fn < 4; ++fn) {
        int n = (wn << 6) + (fn << 4) + (lane & 15);
        bu[fn] = *(const s16x8*)(bulb + (n << 6) + (((lane >> 4) ^ (n & 7)) << 3));
      }
      if (!lastG) {
        gload_lds16(sA[2], dA[2] + ((size_t)wb << 14)); sA[2] += 64;
        gload_lds16(sA[3], dA[3] + ((size_t)wb << 14)); sA[3] += 64;
      }
      SCHED0; SBAR;
      LGKM0; SCHED0;
      __builtin_amdgcn_s_setprio(1);
#pragma unroll
      for (int fm = 0; fm < 4; ++fm)
#pragma unroll
        for (int fn = 0; fn < 4; ++fn)
          au[fm][fn] = __builtin_amdgcn_mfma_f32_16x16x32_bf16(af[fm], bu[fn], au[fm][fn], 0, 0, 0);
      __builtin_amdgcn_s_setprio(0);
      SBAR;
      // P2: ks1 gate
#pragma unroll
      for (int fm = 0; fm < 4; ++fm) {
        int r = (wm << 6) + (fm << 4) + (lane & 15);
        af[fm] = *(const s16x8*)(alb + (r << 6) + (((4 + (lane >> 4)) ^ (r & 7)) << 3));
      }
#pragma unroll
      for (int fn = 0; fn < 4; ++fn) {
        int n = (wn << 6) + (fn << 4) + (lane & 15);
        bg[fn] = *(const s16x8*)(bglb + (n << 6) + (((4 + (lane >> 4)) ^ (n & 7)) << 3));
      }
      if (!lastG) {
        gload_lds16(sG[0], dG[0] + ((size_t)wb << 13)); sG[0] += 64;
        gload_lds16(sG[1], dG[1] + ((size_t)wb << 13)); sG[1] += 64;
      }
      SCHED0; SBAR;
      LGKM0; SCHED0;
      __builtin_amdgcn_s_setprio(1);
#pragma unroll
      for (int fm = 0; fm < 4; ++fm)
#pragma unroll
        for (int fn = 0; fn < 4; ++fn)
          ag[fm][fn] = __builtin_amdgcn_mfma_f32_16x16x32_bf16(af[fm], bg[fn], ag[fm][fn], 0, 0, 0);
      __builtin_amdgcn_s_setprio(0);
      SBAR;
      // P3: ks1 up
#pragma unroll
      for (int fn = 0; fn < 4; ++fn) {
        int n = (wn << 6) + (fn << 4) + (lane & 15);
        bu[fn] = *(const s16x8*)(bulb + (n << 6) + (((4 + (lane >> 4)) ^ (n & 7)) << 3));
      }
      if (!lastG) {
        gload_lds16(sU[0], dU[0] + ((size_t)wb << 13)); sU[0] += 64;
        gload_lds16(sU[1], dU[1] + ((size_t)wb << 13)); sU[1] += 64;
        VMCNT2;
      }
      SCHED0; SBAR;
      LGKM0; SCHED0;
      __builtin_amdgcn_s_setprio(1);
#pragma unroll
      for (int fm = 0; fm < 4; ++fm)
#pragma unroll
        for (int fn = 0; fn < 4; ++fn)
          au[fm][fn] = __builtin_amdgcn_mfma_f32_16x16x32_bf16(af[fm], bu[fn], au[fm][fn], 0, 0, 0);
      __builtin_amdgcn_s_setprio(0);
      SBAR;
    }
    // epilogue
#pragma unroll
    for (int fm = 0; fm < 4; ++fm)
#pragma unroll
      for (int fn = 0; fn < 4; ++fn)
#pragma unroll
        for (int j = 0; j < 4; ++j) {
          int cc = n0 + (wn << 6) + (fn << 4) + (lane & 15);
          if (cc < HH) {
            float gv = ag[fm][fn][j];
            float uv = au[fm][fn][j];
            float hv = gv / (1.f + __expf(-gv)) * uv;
            int r = (wm << 6) + (fm << 4) + ((lane >> 4) << 2) + j;
            hbuf[(row0 + r) * HH + (size_t)cc] = (unsigned short)f2bf1(hv);
          }
          ag[fm][fn][j] = 0.f; au[fm][fn][j] = 0.f;
        }
    if (!hasNext) break;
    row0 = rowNxt; n0 = n0Nxt;
    flat += NBLK;
  }
}

// ---------------- FC2: 128x128 tiles, 4 waves, 2 blocks/CU, y-output (no atomics) ----------------
__global__ __launch_bounds__(256, 2) void k_fc2t(
    const unsigned short* __restrict__ hbuf, const unsigned short* __restrict__ wdT,
    const int* __restrict__ tpfx, unsigned short* __restrict__ y) {
  __shared__ unsigned short Al[2][128 * 64];   // 32 KB
  __shared__ unsigned short Bl[3][128 * 64];   // 48 KB  (total 80 KB -> 2 blocks/CU)
  int ntm = tpfx[EE];
  int nmt2 = ntm << 1;                         // 128-row tiles
  int ntiles = nmt2 << 3;                      // x8 n-panels
  int tid = threadIdx.x, wv = tid >> 6, lane = tid & 63;
  int wm = wv >> 1, wn = wv & 1;               // 2M x 2N, wave 64x64

  int rA_[4], cA8_[4];
  unsigned short* dA[4]; unsigned short* dB[4];
#pragma unroll
  for (int i = 0; i < 4; ++i) {
    int g = (wv << 2) + i;                     // 0..15
    int p = (g << 6) + lane;
    rA_[i] = p >> 3; cA8_[i] = ((p & 7) ^ (rA_[i] & 7)) << 3;
    dA[i] = &Al[0][(size_t)g << 9];
    dB[i] = &Bl[0][(size_t)g << 9];
  }
  unsigned short* Lep = &Bl[0][0];             // epilogue repack buffer (reuses Bl)

  f32x4 zf = {0.f, 0.f, 0.f, 0.f};
  f32x4 acc[4][4];
#pragma unroll
  for (int i = 0; i < 4; ++i)
#pragma unroll
    for (int j = 0; j < 4; ++j) acc[i][j] = zf;

  for (int flat = blockIdx.x; flat < ntiles; flat += NBLK2) {
    int m2 = flat % nmt2, nb = flat / nmt2;
    int seg = m2 >> 1;
    int e = 0;
    while (seg >= tpfx[e + 1]) ++e;
    size_t row0 = ((size_t)seg << 8) + (size_t)((m2 & 1) << 7);
    int n0 = nb << 7;
    const unsigned short* wdE = wdT + (size_t)e * DD * HH;
    const unsigned short* sA[4]; const unsigned short* sB[4];
#pragma unroll
    for (int i = 0; i < 4; ++i) {
      sA[i] = hbuf + (row0 + rA_[i]) * HH + cA8_[i];
      sB[i] = wdE + (size_t)(n0 + rA_[i]) * HH + cA8_[i];
    }
    // prologue: B(0)x4, A(0)x4, B(1)x4
#pragma unroll
    for (int i = 0; i < 4; ++i) { gload_lds16(sB[i], dB[i]); sB[i] += 64; }
#pragma unroll
    for (int i = 0; i < 4; ++i) { gload_lds16(sA[i], dA[i]); sA[i] += 64; }
#pragma unroll
    for (int i = 0; i < 4; ++i) { gload_lds16(sB[i], dB[i] + 8192); sB[i] += 64; }
    VMCNT4;       // B(0)+A(0) landed; B(1) in flight
    SCHED0; SBAR;

    int ca = 0, ib = 0;
    for (int kt = 0; kt < 43; ++kt) {
      bool endA = (kt == 42);
      bool endB = (kt >= 41);
      int wbA = ca ^ 1;
      int ibw = (ib >= 1) ? ib - 1 : 2;        // (ib+2)%3
      const unsigned short* alb = &Al[0][0] + ((size_t)ca << 13);
      const unsigned short* blb = &Bl[0][0] + (size_t)ib * 8192;
      s16x8 af[4], bf[4];
      // ===== P0: ks0 =====
#pragma unroll
      for (int fm = 0; fm < 4; ++fm) {
        int r = (wm << 6) + (fm << 4) + (lane & 15);
        af[fm] = *(const s16x8*)(alb + (r << 6) + (((lane >> 4) ^ (r & 7)) << 3));
      }
#pragma unroll
      for (int fn = 0; fn < 4; ++fn) {
        int n = (wn << 6) + (fn << 4) + (lane & 15);
        bf[fn] = *(const s16x8*)(blb + (n << 6) + (((lane >> 4) ^ (n & 7)) << 3));
      }
      if (!endA) {
#pragma unroll
        for (int i = 0; i < 4; ++i) {
          gload_lds16(sA[i], dA[i] + ((size_t)wbA << 13)); sA[i] += 64;
        }
      }
      SCHED0; SBAR;
      LGKM0; SCHED0;
      __builtin_amdgcn_s_setprio(1);
#pragma unroll
      for (int fm = 0; fm < 4; ++fm)
#pragma unroll
        for (int fn = 0; fn < 4; ++fn)
          acc[fm][fn] = __builtin_amdgcn_mfma_f32_16x16x32_bf16(af[fm], bf[fn], acc[fm][fn], 0, 0, 0);
      __builtin_amdgcn_s_setprio(0);
      SBAR;
      // ===== P1: ks1 =====
#pragma unroll
      for (int fm = 0; fm < 4; ++fm) {
        int r = (wm << 6) + (fm << 4) + (lane & 15);
        af[fm] = *(const s16x8*)(alb + (r << 6) + (((4 + (lane >> 4)) ^ (r & 7)) << 3));
      }
#pragma unroll
      for (int fn = 0; fn < 4; ++fn) {
        int n = (wn << 6) + (fn << 4) + (lane & 15);
        bf[fn] = *(const s16x8*)(blb + (n << 6) + (((4 + (lane >> 4)) ^ (n & 7)) << 3));
      }
      if (!endB) {
#pragma unroll
        for (int i = 0; i < 4; ++i) {
          gload_lds16(sB[i], dB[i] + (size_t)ibw * 8192); sB[i] += 64;
        }
      }
      if (endB) { VMCNT0; } else { VMCNT4; }   // retire A(t+1)+B(t+1); keep B(t+2) in flight
      SCHED0; SBAR;
      LGKM0; SCHED0;
      __builtin_amdgcn_s_setprio(1);
#pragma unroll
      for (int fm = 0; fm < 4; ++fm)
#pragma unroll
        for (int fn = 0; fn < 4; ++fn)
          acc[fm][fn] = __builtin_amdgcn_mfma_f32_16x16x32_bf16(af[fm], bf[fn], acc[fm][fn], 0, 0, 0);
      __builtin_amdgcn_s_setprio(0);
      SBAR;
      ca ^= 1;
      ib = (ib >= 2) ? 0 : ib + 1;
    }
    // epilogue: acc -> LDS repack (pad-130) -> coalesced bf16 y stores
#pragma unroll
    for (int fm = 0; fm < 4; ++fm)
#pragma unroll
      for (int j = 0; j < 4; ++j) {
        int r = (wm << 6) + (fm << 4) + ((lane >> 4) << 2) + j;
#pragma unroll
        for (int fn = 0; fn < 4; ++fn) {
          int c = (wn << 6) + (fn << 4) + (lane & 15);
          Lep[r * 130 + c] = (unsigned short)f2bf1(acc[fm][fn][j]);
          acc[fm][fn][j] = 0.f;
        }
      }
    LGKM0; SBAR;
#pragma unroll
    for (int rep = 0; rep < 8; ++rep) {
      int idx = rep * 256 + tid;
      int r = idx >> 4, ch = idx & 15;
      s16x8 v = *(const s16x8*)(Lep + r * 130 + (ch << 3));
      *(s16x8*)(y + (row0 + r) * DD + (size_t)(n0 + (ch << 3))) = v;
    }
    SBAR;   // protect Lep/Bl before next tile's prologue
  }
}

// ---------------- combine: out[t] = w0*y[r0] + w1*y[r1] ----------------
__global__ void k_combine(const int* __restrict__ topi, const float* __restrict__ topw,
                          const int* __restrict__ tpfx, const unsigned short* __restrict__ y,
                          float* __restrict__ out) {
  int t = (blockIdx.x * blockDim.x + threadIdx.x) >> 6;
  int lane = threadIdx.x & 63;
  int v0 = topi[2 * t], v1 = topi[2 * t + 1];
  int e0 = v0 & 7, e1 = v1 & 7;
  size_t r0 = ((size_t)tpfx[e0] << 8) + (size_t)(v0 >> 3);
  size_t r1 = ((size_t)tpfx[e1] << 8) + (size_t)(v1 >> 3);
  float w0 = topw[2 * t], w1 = topw[2 * t + 1];
  const s16x8* p0 = (const s16x8*)(y + r0 * DD) + (lane << 1);
  const s16x8* p1 = (const s16x8*)(y + r1 * DD) + (lane << 1);
  float4* po = (float4*)(out + (size_t)t * DD) + (lane << 2);
#pragma unroll
  for (int h = 0; h < 2; ++h) {
    s16x8 a = p0[h], b = p1[h];
    float4 o0, o1;
    o0.x = w0 * bf2f((unsigned short)a[0]) + w1 * bf2f((unsigned short)b[0]);
    o0.y = w0 * bf2f((unsigned short)a[1]) + w1 * bf2f((unsigned short)b[1]);
    o0.z = w0 * bf2f((unsigned short)a[2]) + w1 * bf2f((unsigned short)b[2]);
    o0.w = w0 * bf2f((unsigned short)a[3]) + w1 * bf2f((unsigned short)b[3]);
    o1.x = w0 * bf2f((unsigned short)a[4]) + w1 * bf2f((unsigned short)b[4]);
    o1.y = w0 * bf2f((unsigned short)a[5]) + w1 * bf2f((unsigned short)b[5]);
    o1.z = w0 * bf2f((unsigned short)a[6]) + w1 * bf2f((unsigned short)b[6]);
    o1.w = w0 * bf2f((unsigned short)a[7]) + w1 * bf2f((unsigned short)b[7]);
    po[2 * h] = o0; po[2 * h + 1] = o1;
  }
}

// ================= fallback kernels (128-row tiles over 256-aligned segments) =================
__global__ __launch_bounds__(256) void k_fc1_cv(
    const unsigned short* __restrict__ Xg, const float* __restrict__ wg,
    const float* __restrict__ wu, const int* __restrict__ tpfx,
    unsigned short* __restrict__ hbuf) {
  __shared__ unsigned short Al[128 * 64];
  __shared__ unsigned short Bgl[64 * 64];
  __shared__ unsigned short Bul[64 * 64];
  int mt = blockIdx.x;
  if (mt >= 2 * tpfx[EE]) return;
  int e = 0;
  while (mt >= 2 * tpfx[e + 1]) ++e;
  int n0 = blockIdx.y << 6;
  size_t row0 = (size_t)mt << 7;
  const float* wge = wg + (size_t)e * DD * HH;
  const float* wue = wu + (size_t)e * DD * HH;
  int tid = threadIdx.x, wv = tid >> 6, lane = tid & 63;
  int wm = wv >> 1, wn = wv & 1;
  f32x4 zf = {0.f, 0.f, 0.f, 0.f};
  f32x4 ag[4][2], au[4][2];
#pragma unroll
  for (int i = 0; i < 4; ++i)
#pragma unroll
    for (int j = 0; j < 2; ++j) { ag[i][j] = zf; au[i][j] = zf; }
  for (int kt = 0; kt < DD / 64; ++kt) {
    int k0 = kt << 6;
#pragma unroll
    for (int i = 0; i < 4; ++i) {
      int g = (wv << 2) + i;
      int p = (g << 6) + lane;
      int r = p >> 3, c = (p & 7) ^ (r & 7);
      gload_lds16(Xg + (row0 + r) * DD + (size_t)(k0 + (c << 3)), Al + ((size_t)g << 9));
    }
#pragma unroll
    for (int a2 = 0; a2 < 2; ++a2) {
      int idx = tid + (a2 << 8);
      int kk = (idx >> 4) << 1;
      int nn = (idx & 15) << 2;
      const float* pg = wge + (size_t)(k0 + kk) * HH + (n0 + nn);
      const float* pu = wue + (size_t)(k0 + kk) * HH + (n0 + nn);
      float4 g0 = *(const float4*)pg;
      float4 g1 = *(const float4*)(pg + HH);
      float4 u0 = *(const float4*)pu;
      float4 u1 = *(const float4*)(pu + HH);
      const float* g0f = (const float*)&g0; const float* g1f = (const float*)&g1;
      const float* u0f = (const float*)&u0; const float* u1f = (const float*)&u1;
      int kb = kk << 1, ch = kb >> 4, inb = kb & 15;
#pragma unroll
      for (int j = 0; j < 4; ++j) {
        int n = nn + j;
        int off = (n << 7) + ((ch ^ bswz(n)) << 4) + inb;
        *(unsigned int*)((char*)Bgl + off) = f2bf2(g0f[j], g1f[j]);
        *(unsigned int*)((char*)Bul + off) = f2bf2(u0f[j], u1f[j]);
      }
    }
    __syncthreads();
#pragma unroll
    for (int ks = 0; ks < 2; ++ks) {
      int cch = (ks << 2) + (lane >> 4);
      s16x8 af[4];
#pragma unroll
      for (int fm = 0; fm < 4; ++fm) {
        int r = (wm << 6) + (fm << 4) + (lane & 15);
        af[fm] = *(const s16x8*)(Al + (r << 6) + ((cch ^ (r & 7)) << 3));
      }
      s16x8 bg[2], bu[2];
#pragma unroll
      for (int fn = 0; fn < 2; ++fn) {
        int n = (wn << 5) + (fn << 4) + (lane & 15);
        int o = (n << 6) + ((cch ^ bswz(n)) << 3);
        bg[fn] = *(const s16x8*)(Bgl + o);
        bu[fn] = *(const s16x8*)(Bul + o);
      }
#pragma unroll
      for (int fm = 0; fm < 4; ++fm)
#pragma unroll
        for (int fn = 0; fn < 2; ++fn) {
          ag[fm][fn] = __builtin_amdgcn_mfma_f32_16x16x32_bf16(af[fm], bg[fn], ag[fm][fn], 0, 0, 0);
          au[fm][fn] = __builtin_amdgcn_mfma_f32_16x16x32_bf16(af[fm], bu[fn], au[fm][fn], 0, 0, 0);
        }
    }
    __syncthreads();
  }
#pragma unroll
  for (int fm = 0; fm < 4; ++fm)
#pragma unroll
    for (int fn = 0; fn < 2; ++fn)
#pragma unroll
      for (int j = 0; j < 4; ++j) {
        float gv = ag[fm][fn][j];
        float uv = au[fm][fn][j];
        float hv = gv / (1.f + __expf(-gv)) * uv;
        int r = (wm << 6) + (fm << 4) + ((lane >> 4) << 2) + j;
        int cc = (wn << 5) + (fn << 4) + (lane & 15);
        hbuf[(row0 + r) * HH + (size_t)(n0 + cc)] = (unsigned short)f2bf1(hv);
      }
}

__global__ __launch_bounds__(256) void k_fc2_cv(
    const unsigned short* __restrict__ hbuf, const float* __restrict__ wd,
    const int* __restrict__ cnt, const int* __restrict__ tpfx,
    const int* __restrict__ tok, const float* __restrict__ wgt,
    float* __restrict__ out) {
  __shared__ unsigned short Al[128 * 64];
  __shared__ unsigned short Bl[128 * 64];
  int mt = blockIdx.x;
  if (mt >= 2 * tpfx[EE]) return;
  int e = 0;
  while (mt >= 2 * tpfx[e + 1]) ++e;
  int n0 = blockIdx.y << 7;
  size_t row0 = (size_t)mt << 7;
  int mrem = cnt[e] - ((mt - 2 * tpfx[e]) << 7);
  if (mrem > 128) mrem = 128;
  const float* wde = wd + (size_t)e * HH * DD;
  int tid = threadIdx.x, wv = tid >> 6, lane = tid & 63;
  int wm = wv >> 1, wn = wv & 1;
  f32x4 zf = {0.f, 0.f, 0.f, 0.f};
  f32x4 acc[4][4];
#pragma unroll
  for (int i = 0; i < 4; ++i)
#pragma unroll
    for (int j = 0; j < 4; ++j) acc[i][j] = zf;
  for (int kt = 0; kt < HH / 64; ++kt) {
    int k0 = kt << 6;
#pragma unroll
    for (int i = 0; i < 4; ++i) {
      int g = (wv << 2) + i;
      int p = (g << 6) + lane;
      int r = p >> 3, c = (p & 7) ^ (r & 7);
      gload_lds16(hbuf + (row0 + r) * HH + (size_t)(k0 + (c << 3)), Al + ((size_t)g << 9));
    }
#pragma unroll
    for (int a2 = 0; a2 < 4; ++a2) {
      int idx = tid + (a2 << 8);
      int kk = (idx >> 5) << 1;
      int nn = (idx & 31) << 2;
      const float* pb = wde + (size_t)(k0 + kk) * DD + (n0 + nn);
      float4 b0 = *(const float4*)pb;
      float4 b1 = *(const float4*)(pb + DD);
      const float* b0f = (const float*)&b0;
      const float* b1f = (const float*)&b1;
      int kb = kk << 1, ch = kb >> 4, inb = kb & 15;
#pragma unroll
      for (int j = 0; j < 4; ++j) {
        int n = nn + j;
        int off = (n << 7) + ((ch ^ bswz(n)) << 4) + inb;
        *(unsigned int*)((char*)Bl + off) = f2bf2(b0f[j], b1f[j]);
      }
    }
    __syncthreads();
#pragma unroll
    for (int ks = 0; ks < 2; ++ks) {
      int cch = (ks << 2) + (lane >> 4);
      s16x8 af[4], bf[4];
#pragma unroll
      for (int fm = 0; fm < 4; ++fm) {
        int r = (wm << 6) + (fm << 4) + (lane & 15);
        af[fm] = *(const s16x8*)(Al + (r << 6) + ((cch ^ (r & 7)) << 3));
      }
#pragma unroll
      for (int fn = 0; fn < 4; ++fn) {
        int n = (wn << 6) + (fn << 4) + (lane & 15);
        bf[fn] = *(const s16x8*)(Bl + (n << 6) + ((cch ^ bswz(n)) << 3));
      }
#pragma unroll
      for (int fm = 0; fm < 4; ++fm)
#pragma unroll
        for (int fn = 0; fn < 4; ++fn)
          acc[fm][fn] = __builtin_amdgcn_mfma_f32_16x16x32_bf16(af[fm], bf[fn], acc[fm][fn], 0, 0, 0);
    }
    __syncthreads();
  }
#pragma unroll
  for (int fm = 0; fm < 4; ++fm)
#pragma unroll
    for (int j = 0; j < 4; ++j) {
      int r = (wm << 6) + (fm << 4) + ((lane >> 4) << 2) + j;
      if (r < mrem) {
        int tk = tok[row0 + r];
        float cw = wgt[row0 + r];
        float* ob = out + (size_t)tk * DD + (size_t)(n0 + (wn << 6) + (lane & 15));
#pragma unroll
        for (int fn = 0; fn < 4; ++fn)
          atomicAdd(ob + (fn << 4), acc[fm][fn][j] * cw);
      }
    }
}

extern "C" void kernel_launch(void* const* d_in, const int* in_sizes, int n_in,
                              void* d_out, int out_size, void* d_ws, size_t ws_size,
                              hipStream_t stream) {
  const float* x  = (const float*)d_in[0];
  const float* rw = (const float*)d_in[1];
  const float* wg = (const float*)d_in[2];
  const float* wu = (const float*)d_in[3];
  const float* wd = (const float*)d_in[4];
  float* out = (float*)d_out;

  // workspace layout (256-row padded segments; max 18432 gathered rows)
  char* w = (char*)d_ws;
  int* cnt    = (int*)(w + 0);
  int* cursor = (int*)(w + 32);
  int* tpfx   = (int*)(w + 64);
  int* topi   = (int*)(w + 256);                      // 16384 ints
  float* topw = (float*)(w + 65792);                  // 16384 f32
  int* tok    = (int*)(w + 131328);                   // 18432 ints
  float* wgt  = (float*)(w + 205056);                 // 18432 f32
  unsigned short* Xg  = (unsigned short*)(w + 278784);        // 37,748,736 B (reused as y after fc1)
  unsigned short* hb  = (unsigned short*)(w + 38027520ULL);   // 101,449,728 B
  unsigned short* wgT = (unsigned short*)(w + 139477248ULL);  // 45,088,768 B
  unsigned short* wuT = (unsigned short*)(w + 184566016ULL);  // 45,088,768 B
  unsigned short* wdT2 = (unsigned short*)(w + 229654784ULL); // 45,088,768 B (big path)
  const size_t NEED  = 229654784ULL;                  // mid path (wdT reuses wgT)
  const size_t NEED2 = 274743552ULL;                  // big path (separate wdT)

  bool mid = ws_size >= NEED;
  bool big = ws_size >= NEED2;

  int prep_grid = NRB + (big ? 3 * NTB : (mid ? 2 * NTB : 0));
  k_prep<<<prep_grid, 256, 0, stream>>>(x, rw, topi, topw, cursor,
                                        wg, wgT, wu, wuT, wd, wdT2);
  k_assign<<<T_TOKENS / 256, 256, 0, stream>>>(topi, cursor);
  k_offsets<<<1, 64, 0, stream>>>(cursor, cnt, tpfx);
  k_copy_pad<<<2560, 256, 0, stream>>>(x, topi, topw, tpfx, cnt, tok, wgt, Xg);

  if (mid) {
    k_fc1t<<<NBLK, 512, 0, stream>>>(Xg, wgT, wuT, tpfx, hb);
    unsigned short* wdTp = wdT2;
    if (!big) {
      k_wtrans<<<NTB, 256, 0, stream>>>(wd, wgT, HH, DD);  // over wgT slot
      wdTp = wgT;
    }
    unsigned short* y = Xg;   // Xg is dead after fc1
    k_fc2t<<<NBLK2, 256, 0, stream>>>(hb, wdTp, tpfx, y);
    k_combine<<<T_TOKENS / 4, 256, 0, stream>>>(topi, topw, tpfx, y, out);
  } else {
    hipMemsetAsync(d_out, 0, (size_t)T_TOKENS * DD * sizeof(float), stream);
    k_fc1_cv<<<dim3(MT1, HH / 64), 256, 0, stream>>>(Xg, wg, wu, tpfx, hb);
    k_fc2_cv<<<dim3(MT1, DD / 128), 256, 0, stream>>>(hb, wd, cnt, tpfx, tok, wgt, out);
  }
}